// Round 7
// baseline (1143.737 us; speedup 1.0000x reference)
//
#include <hip/hip_runtime.h>
#include <hip/hip_bf16.h>

// ---------------------------------------------------------------------------
// Equivariant conv block. MFMA 32x32x16 implicit GEMM.
// R15 post-mortem: concept OK (passed), but s8 Ba[14]/Bb[14] arrays went to
// SCRATCH (rule #20: runtime-indexable ext_vector arrays): WRITE_SIZE 16->714
// MB, conv 406us. R16 = R15 with B in 28 INDIVIDUALLY NAMED s8 registers and
// fully macro-expanded load/compute (every access compile-time constant).
// B loaded per-wave to regs (wave-identical operand, coalesced 1KB/load-inst),
// double-set software pipeline 1 tap ahead. Barriers ONLY at A-parity flips:
// 2 per 7 taps (18 total vs 63). LDS 46KB = A-stripe only; grid 512 =
// 2 blocks/CU. Cost: 4x wl L2 redundancy (~1.8GB < L2 ceiling over 100us).
// ---------------------------------------------------------------------------

using f4  = __attribute__((ext_vector_type(4)))  float;
using f16v= __attribute__((ext_vector_type(16))) float;
using s8  = __attribute__((ext_vector_type(8)))  short;  // 8 bf16

#define C_TOT 160
#define PZ_   37
#define NTAP  343
#define NROW  (4 * PZ_ * PZ_)   // 5476 (b,z,y) rows per chunk
#define KSN   8
#define SLICE_E 1048576         // bf16 elems per partial slice (4*64*4096)

// conv LDS: A-stripe only. Rows 1216 B data + 16 pad = 1232 stride, split by
// y'-parity: A_E = 19 rows (y'=0,2,..,36) at [0, 23552); A_O = 18 rows at
// [23552, 46080). Total 46080 (2 blocks/CU trivially).
// Epilogue reuses [0, 33792) as yb[64n][33 f4].
#define AROW    1232
#define AE_ROWS 19
#define AO_ROWS 18
#define AO_OFF  23552
#define LDS_SZ  46080

__device__ __forceinline__ void gl_lds16(const void* g, void* l) {
    __builtin_amdgcn_global_load_lds(
        (const __attribute__((address_space(1))) unsigned int*)g,
        (__attribute__((address_space(3))) unsigned int*)l, 16, 0, 0);
}

__device__ __forceinline__ void pair_ij(int p, int& i, int& j) {
    if (p < 3)      { i = p; j = p; }
    else if (p == 3){ i = 0; j = 1; }
    else if (p == 4){ i = 0; j = 2; }
    else            { i = 1; j = 2; }
}

struct bf2 { __hip_bfloat16 x, y; };
struct bh4 { __hip_bfloat16 x, y, z, w; };

// ---------------------------------------------------------------------------
// Merged prep: bid < 1372 -> build_w (tap = bid>>2, j-quarter), else build_xt.
// xt[chunk][brow][s][16ch], brow=(b*37+z)*37+y.  wl[chunk][tap][n][16ch].
// ---------------------------------------------------------------------------
__global__ void prep_kernel(
    const float* __restrict__ sv,
    const float* __restrict__ b_ss, const float* __restrict__ w_ss,
    const float* __restrict__ b_sv, const float* __restrict__ w_sv,
    const float* __restrict__ b_st, const float* __restrict__ w_st,
    const float* __restrict__ b_vs, const float* __restrict__ w_vs,
    const float* __restrict__ b_vv, const float* __restrict__ w_vv,
    const float* __restrict__ b_vt, const float* __restrict__ w_vt,
    __hip_bfloat16* __restrict__ xt, __hip_bfloat16* __restrict__ wl)
{
    __shared__ float S[13056];
    const int tid = threadIdx.x;

    if (blockIdx.x < 1372) {
        // ---------------- build_w ----------------
        float* L = S;           // 750
        float* W = S + 768;     // 12288
        const int tap = blockIdx.x >> 2;
        const int jq  = (blockIdx.x & 3) * 10;
        for (int r = tid; r < 750; r += 256) {
            float v;
            if (r < 3)        v = b_ss[r * NTAP + tap];
            else if (r < 12)  v = b_sv[(r - 3) * NTAP + tap];
            else if (r < 93)  v = b_st[(r - 12) * NTAP + tap];
            else if (r < 102) v = b_vs[(r - 93) * NTAP + tap];
            else if (r < 183) v = b_vv[(r - 102) * NTAP + tap];
            else              v = b_vt[(r - 183) * NTAP + tap];
            L[r] = v;
        }
        for (int r = tid; r < 12288; r += 256) {
            float v;
            if (r < 768)       v = w_ss[r];
            else if (r < 1536) v = w_sv[r - 768];
            else if (r < 3840) v = w_st[r - 1536];
            else if (r < 4608) v = w_vs[r - 3840];
            else if (r < 6912) v = w_vv[r - 4608];
            else               v = w_vt[r - 6912];
            W[r] = v;
        }
        __syncthreads();
        for (int j = jq; j < jq + 10; ++j) {
            const int idx = j * 256 + tid;
            const int c = idx % C_TOT, n = idx / C_TOT;
            float acc = 0.f;
            if (n < 16) {
                const int u = n;
                if (c < 16) {
                    for (int t = 0; t < 3; ++t) acc += W[(u*16 + c)*3 + t] * L[t];
                } else if (c < 64) {
                    int mm = (c-16)/3, di = (c-16)%3;
                    for (int t = 0; t < 3; ++t)
                        acc += W[768 + (u*16+mm)*3 + t] * L[3 + t*3 + di];
                } else {
                    int q = c-64, mm = q/6, p = q%6, i, jj;
                    pair_ij(p, i, jj);
                    int d1 = i*3+jj, d2 = jj*3+i;
                    for (int t = 0; t < 9; ++t) {
                        float bs = L[12 + t*9 + d1];
                        if (i != jj) bs += L[12 + t*9 + d2];
                        acc += W[1536 + (u*16+mm)*9 + t] * bs;
                    }
                }
            } else {
                const int u = (n-16)/3, dn = (n-16)%3;
                if (c < 16) {
                    for (int t = 0; t < 3; ++t)
                        acc += W[3840 + (u*16+c)*3 + t] * L[93 + t*3 + dn];
                } else if (c < 64) {
                    int mm = (c-16)/3, di = (c-16)%3;
                    for (int t = 0; t < 9; ++t)
                        acc += W[4608 + (u*16+mm)*9 + t] * L[102 + (t*3+dn)*3 + di];
                } else {
                    int q = c-64, mm = q/6, p = q%6, i, jj;
                    pair_ij(p, i, jj);
                    int d1 = i*3+jj, d2 = jj*3+i;
                    for (int t = 0; t < 21; ++t) {
                        float bs = L[183 + (t*3+dn)*9 + d1];
                        if (i != jj) bs += L[183 + (t*3+dn)*9 + d2];
                        acc += W[6912 + (u*16+mm)*21 + t] * bs;
                    }
                }
            }
            const int chunk = c >> 4, cw = c & 15;
            wl[((size_t)chunk * NTAP + tap) * 1024 + (size_t)n * 16 + cw] =
                __float2bfloat16(acc);
        }
    } else {
        // ---------------- build_xt ----------------
        float* row = S;                              // 32*66 = 2112
        const int bid = blockIdx.x - 1372;           // (b*37 + z)*37 + y
        const int y = bid % 37, z = (bid / 37) % 37, b = bid / 1369;
        const bool interior = (z >= 3 && z < 35 && y >= 3 && y < 35);
        if (interior) {
            const float* src = sv + (size_t)b * 2097152 + (z-3) * 1024 + (y-3) * 32;
            for (int f = tid; f < 2048; f += 256) {
                int ch = f >> 5, x = f & 31;
                row[x * 66 + ch] = src[(size_t)ch * 32768 + x];
            }
        }
        __syncthreads();
        for (int e2 = tid; e2 < 38 * 80; e2 += 256) {
            const int s = e2 / 80, cp = e2 % 80, c = cp * 2;
            float v0 = 0.f, v1 = 0.f;
            if (interior && s >= 3 && s < 35) {
                const int x = s - 3;
                if (c < 64) {
                    v0 = row[x * 66 + c];
                    v1 = row[x * 66 + c + 1];
                } else {
                    int q = c - 64, u = q / 6, p = q % 6, i, j;
                    pair_ij(p, i, j);
                    v0 = row[x * 66 + 16 + u * 3 + i] * row[x * 66 + 16 + u * 3 + j];
                    pair_ij(p + 1, i, j);
                    v1 = row[x * 66 + 16 + u * 3 + i] * row[x * 66 + 16 + u * 3 + j];
                }
            }
            bf2 w{__float2bfloat16(v0), __float2bfloat16(v1)};
            const int chunk = c >> 4, cw = c & 15;
            *(bf2*)(xt + ((size_t)chunk * NROW + bid) * 608 + s * 16 + cw) = w;
        }
    }
}

// ---------------------------------------------------------------------------
// Conv. Grid 512 (2 blocks/CU). Block = (b, oz, ks). K groups g=(chunk,kz) =
// ks..69 step 8; per group A-stripe (37 xt rows) staged once, parity split;
// taps ky = 1,3,5,0,2,4,6. Barriers ONLY at p==0 and p==3 (2 per 7 taps).
// B in named registers, double-set software pipeline (1 tap ahead).
// ---------------------------------------------------------------------------

#define B_DECL(P) s8 P##0, P##1, P##2, P##3, P##4, P##5, P##6, \
                     P##7, P##8, P##9, P##10, P##11, P##12, P##13

#define LOADB(P, g_, ky_) do {                                                \
    const int ch_ = (g_) / 7, kz_ = (g_) - ch_ * 7;                           \
    const __hip_bfloat16* wb_ = wlb                                           \
        + ((size_t)ch_ * NTAP + (size_t)(kz_ * 7 + (ky_)) * 7) * 1024;        \
    P##0  = *(const s8*)(wb_);          P##1  = *(const s8*)(wb_ + 512);      \
    P##2  = *(const s8*)(wb_ + 1024);   P##3  = *(const s8*)(wb_ + 1536);     \
    P##4  = *(const s8*)(wb_ + 2048);   P##5  = *(const s8*)(wb_ + 2560);     \
    P##6  = *(const s8*)(wb_ + 3072);   P##7  = *(const s8*)(wb_ + 3584);     \
    P##8  = *(const s8*)(wb_ + 4096);   P##9  = *(const s8*)(wb_ + 4608);     \
    P##10 = *(const s8*)(wb_ + 5120);   P##11 = *(const s8*)(wb_ + 5632);     \
    P##12 = *(const s8*)(wb_ + 6144);   P##13 = *(const s8*)(wb_ + 6656);     \
} while (0)

#define CSTEP(b0_, b1_, kx_) {                                                \
    const int s_   = sbase + (kx_);                                           \
    const int cgp_ = h ^ ((s_ >> 1) & 1);                                     \
    const char* ap_ = abp_ + s_ * 32 + cgp_ * 16;                             \
    const s8 a0_ = *(const s8*)(ap_);                                         \
    const s8 a1_ = *(const s8*)(ap_ + 8 * AROW);                              \
    acc[0][0] = __builtin_amdgcn_mfma_f32_32x32x16_bf16(a0_, b0_, acc[0][0], 0, 0, 0); \
    acc[0][1] = __builtin_amdgcn_mfma_f32_32x32x16_bf16(a0_, b1_, acc[0][1], 0, 0, 0); \
    acc[1][0] = __builtin_amdgcn_mfma_f32_32x32x16_bf16(a1_, b0_, acc[1][0], 0, 0, 0); \
    acc[1][1] = __builtin_amdgcn_mfma_f32_32x32x16_bf16(a1_, b1_, acc[1][1], 0, 0, 0); \
}

#define COMPT(P, ky_) do {                                                    \
    const char* abp_ = lds + (((ky_) & 1) ? AO_OFF : 0)                       \
                     + (rA0 + ((ky_) >> 1)) * AROW;                           \
    CSTEP(P##0,  P##1,  0) CSTEP(P##2,  P##3,  1) CSTEP(P##4,  P##5,  2)      \
    CSTEP(P##6,  P##7,  3) CSTEP(P##8,  P##9,  4) CSTEP(P##10, P##11, 5)      \
    CSTEP(P##12, P##13, 6)                                                    \
} while (0)

__global__ __launch_bounds__(256, 2) void conv_mfma_kernel(
    const __hip_bfloat16* __restrict__ xt,
    const __hip_bfloat16* __restrict__ wl,
    __hip_bfloat16* __restrict__ y4b)
{
    __shared__ __align__(16) char lds[LDS_SZ];

    // T1 XCD swizzle: grid = 512 = 8 XCDs x 64.
    const int phys = blockIdx.x;
    const int bid  = (phys & 7) * (64 * KSN / 8) + (phys >> 3);

    const int low3 = bid & 7;
    const int rest = bid >> 3;
    const int ks   = rest % KSN;
    const int mb   = (rest / KSN) * 8 + low3;   // 0..63
    const int b    = mb >> 4;                   // 0..3
    const int oz   = mb & 15;                   // z-out 0..15

    const int tid  = threadIdx.x;
    const int w    = tid >> 6;          // x-quarter
    const int lane = tid & 63;
    const int m    = lane & 31;
    const int h    = lane >> 5;         // k-half (8-ch group)

    // ---- per-lane invariant staging source offsets (elements) ----
    int invAE[6]; int nAE = 0;
#pragma unroll
    for (int k = 0; k < 6; ++k) {
        const int i = w + 4 * k;
        if (i < 23) {
            const int o = i * 1024 + lane * 16;
            int r = o / AROW;
            int rem = o - r * AROW;
            if (r > AE_ROWS - 1) { r = AE_ROWS - 1; rem = 0; }
            if (rem >= 1216) rem = 0;
            const int s  = rem >> 5;
            const int cg = ((rem >> 4) & 1) ^ ((s >> 1) & 1);
            invAE[k] = (2 * r) * 608 + s * 16 + cg * 8;      // y' = 2r
            nAE = k + 1;
        }
    }
    int invAO[6]; int nAO = 0;
#pragma unroll
    for (int k = 0; k < 6; ++k) {
        const int i = w + 4 * k;
        if (i < 22) {
            const int o = i * 1024 + lane * 16;
            int r = o / AROW;
            int rem = o - r * AROW;
            if (r > AO_ROWS - 1) { r = AO_ROWS - 1; rem = 0; }
            if (rem >= 1216) rem = 0;
            const int s  = rem >> 5;
            const int cg = ((rem >> 4) & 1) ^ ((s >> 1) & 1);
            invAO[k] = (2 * r + 1) * 608 + s * 16 + cg * 8;  // y' = 2r+1
            nAO = k + 1;
        }
    }

    const __hip_bfloat16* wlb = wl + (size_t)(m * 16 + h * 8);

    f16v acc[2][2];
    for (int t = 0; t < 2; ++t)
        for (int n = 0; n < 2; ++n)
            for (int k = 0; k < 16; ++k) acc[t][n][k] = 0.f;

    const int rA0   = ((m >> 4) << 2) + ((m >> 2) & 3);   // yo base 0..7
    const int sbase = (w << 3) + ((m & 3) << 1);          // + kx -> x slot

    auto stageAE = [&](int g) {
        const int chunk = g / 7, kz = g - chunk * 7;
        const size_t u = ((size_t)chunk * NROW
                        + (size_t)(b * PZ_ + 2 * oz + kz) * PZ_) * 608;
#pragma unroll
        for (int k = 0; k < 6; ++k)
            if (k < nAE) gl_lds16(xt + u + invAE[k], lds + (w + 4 * k) * 1024);
    };
    auto stageAO = [&](int g) {
        const int chunk = g / 7, kz = g - chunk * 7;
        const size_t u = ((size_t)chunk * NROW
                        + (size_t)(b * PZ_ + 2 * oz + kz) * PZ_) * 608;
#pragma unroll
        for (int k = 0; k < 6; ++k)
            if (k < nAO) gl_lds16(xt + u + invAO[k], lds + AO_OFF + (w + 4 * k) * 1024);
    };

    // ---- main loop ----
    const int G = (70 - ks + KSN - 1) / KSN;   // ks 0..5 -> 9, 6..7 -> 8
    const int T = G * 7;
    B_DECL(Ba);  B_DECL(Bb);
    stageAO(ks);
    LOADB(Ba, ks, 1);                 // tap 0 = (ks, ky=1)
    bool useA = true;
    for (int t = 0; t < T; ++t) {
        const int gi = t / 7, p = t - gi * 7;
        const int g  = ks + gi * KSN;
        if (p == 0)      { __syncthreads(); stageAE(g); }
        else if (p == 3) { __syncthreads(); if (g + KSN < 70) stageAO(g + KSN); }
        const int ky = (p < 3) ? (2 * p + 1) : (2 * (p - 3));
        const int tn = t + 1;
        int gn = 0, kyn = 0;
        const bool hasN = (tn < T);
        if (hasN) {
            const int gin = tn / 7, pn = tn - gin * 7;
            gn  = ks + gin * KSN;
            kyn = (pn < 3) ? (2 * pn + 1) : (2 * (pn - 3));
        }
        if (useA) {
            if (hasN) LOADB(Bb, gn, kyn);
            COMPT(Ba, ky);
        } else {
            if (hasN) LOADB(Ba, gn, kyn);
            COMPT(Bb, ky);
        }
        useA = !useA;
    }

    // ---- epilogue: two-pass LDS transpose, coalesced bf16 partial stores ----
    // C/D 32x32: col(n)=lane&31, row m32=(reg&3)+8*(reg>>2)+4*h  [m74/m101]
    const int nl = lane & 31;
    f4* yb = (f4*)lds;                  // [64n][33 f4] padded = 33792 B
    __hip_bfloat16* dst0 = y4b + (size_t)ks * SLICE_E + (size_t)(b * 64) * 4096;
#pragma unroll
    for (int t = 0; t < 2; ++t) {       // yo-half
        __syncthreads();                // prior readers (or compute) done
#pragma unroll
        for (int nt = 0; nt < 2; ++nt) {
            const int n = nt * 32 + nl;
#pragma unroll
            for (int q = 0; q < 4; ++q) {
                const int rr = 2 * q + h;
                f4 v = { acc[t][nt][4*q], acc[t][nt][4*q+1],
                         acc[t][nt][4*q+2], acc[t][nt][4*q+3] };
                yb[n * 33 + rr * 4 + w] = v;
            }
        }
        __syncthreads();
        for (int j = tid; j < 2048; j += 256) {
            const int n  = j >> 5, sp = j & 31;    // sp = rr*4 + wq
            f4 v = yb[n * 33 + sp];
            const int rr = sp >> 2, wq = sp & 3;
            const int yo = t * 8 + (rr >> 2) * 4 + (rr & 3);
            bh4 p{__float2bfloat16(v.x), __float2bfloat16(v.y),
                  __float2bfloat16(v.z), __float2bfloat16(v.w)};
            *(bh4*)(dst0 + (size_t)n * 4096 + oz * 256 + yo * 16 + wq * 4) = p;
        }
    }
}

// ---------------------------------------------------------------------------
// Combine KSN bf16 partials -> f32 yc + per-(n,b) sum of squares. 256 blocks.
// ---------------------------------------------------------------------------
__global__ void combine_reduce_kernel(const __hip_bfloat16* __restrict__ y4b,
                                      float* __restrict__ yc,
                                      float* __restrict__ sums2)
{
    const int n = blockIdx.x & 63, q = blockIdx.x >> 6;
    const size_t base = ((size_t)q * 64 + n) * 4096;
    float s = 0.f;
    for (int i = threadIdx.x; i < 1024; i += 256) {
        const size_t off = base + (size_t)i * 4;
        f4 v = {0.f, 0.f, 0.f, 0.f};
#pragma unroll
        for (int k = 0; k < KSN; ++k) {
            bh4 r = *(const bh4*)(y4b + off + (size_t)k * SLICE_E);
            v.x += (float)r.x; v.y += (float)r.y;
            v.z += (float)r.z; v.w += (float)r.w;
        }
        *(f4*)(yc + off) = v;
        s += v.x * v.x + v.y * v.y + v.z * v.z + v.w * v.w;
    }
    __shared__ float red[256];
    red[threadIdx.x] = s;
    __syncthreads();
    for (int st = 128; st > 0; st >>= 1) {
        if (threadIdx.x < st) red[threadIdx.x] += red[threadIdx.x + st];
        __syncthreads();
    }
    if (threadIdx.x == 0) sums2[n * 4 + q] = red[0];
}

// ---------------------------------------------------------------------------
__global__ void finalize_kernel(const float* __restrict__ yc,
                                const float* __restrict__ sums2,
                                const float* __restrict__ g_s,
                                const float* __restrict__ g_v,
                                const float* __restrict__ bias_s,
                                float* __restrict__ out)
{
    const int idx = blockIdx.x * 256 + threadIdx.x;   // exact grid, 1M
    const int n = (idx >> 12) & 63;
    float v = yc[idx];
    if (n < 16) {
        float sum = sums2[n*4] + sums2[n*4+1] + sums2[n*4+2] + sums2[n*4+3];
        float var = sum * (1.0f / 16384.0f);
        float sc  = g_s[n] / sqrtf(var + 1e-5f);
        v = fmaxf(v * sc + bias_s[n], 0.f);
    } else {
        int u = (n - 16) / 3;
        float sum = 0.f;
        for (int k = 0; k < 12; ++k) sum += sums2[(16 + u * 3) * 4 + k];
        float var = sum * (1.0f / 49152.0f);
        v = v * (g_v[u] / sqrtf(var + 1e-5f));
    }
    out[idx] = v;
}

// ---------------------------------------------------------------------------
extern "C" void kernel_launch(void* const* d_in, const int* in_sizes, int n_in,
                              void* d_out, int out_size, void* d_ws, size_t ws_size,
                              hipStream_t stream)
{
    const float* sv    = (const float*)d_in[0];
    const float* b_ss  = (const float*)d_in[1];
    const float* w_ss  = (const float*)d_in[2];
    const float* b_sv  = (const float*)d_in[3];
    const float* w_sv  = (const float*)d_in[4];
    const float* b_st  = (const float*)d_in[5];
    const float* w_st  = (const float*)d_in[6];
    const float* b_vs  = (const float*)d_in[7];
    const float* w_vs  = (const float*)d_in[8];
    const float* b_vv  = (const float*)d_in[9];
    const float* w_vv  = (const float*)d_in[10];
    const float* b_vt  = (const float*)d_in[11];
    const float* w_vt  = (const float*)d_in[12];
    const float* bn_gs = (const float*)d_in[13];
    const float* bn_gv = (const float*)d_in[14];
    const float* bias_s= (const float*)d_in[15];
    float* out = (float*)d_out;

    char* ws = (char*)d_ws;
    constexpr size_t XT_BYTES = (size_t)10 * NROW * 1216;      // 66,588,160
    constexpr size_t WL_BYTES = (size_t)10 * NTAP * 2048;      //  7,024,640
    constexpr size_t Y4_BYTES = (size_t)KSN * SLICE_E * 2;     // 16,777,216
    constexpr size_t YC_BYTES = (size_t)4 * 64 * 4096 * 4;     //  4,194,304

    __hip_bfloat16* xt  = (__hip_bfloat16*)ws;
    __hip_bfloat16* wl  = (__hip_bfloat16*)(ws + XT_BYTES);
    __hip_bfloat16* y4b = (__hip_bfloat16*)(ws + XT_BYTES + WL_BYTES);
    float* yc    = (float*)(ws + XT_BYTES + WL_BYTES + Y4_BYTES);
    float* sums2 = (float*)(ws + XT_BYTES + WL_BYTES + Y4_BYTES + YC_BYTES);

    prep_kernel<<<1372 + 5476, 256, 0, stream>>>(
        sv, b_ss, w_ss, b_sv, w_sv, b_st, w_st, b_vs, w_vs, b_vv, w_vv,
        b_vt, w_vt, xt, wl);
    conv_mfma_kernel<<<64 * KSN, 256, 0, stream>>>(xt, wl, y4b);
    combine_reduce_kernel<<<256, 256, 0, stream>>>(y4b, yc, sums2);
    finalize_kernel<<<4096, 256, 0, stream>>>(yc, sums2, bn_gs, bn_gv, bias_s, out);
}

// Round 8
// 317.925 us; speedup vs baseline: 3.5975x; 3.5975x over previous
//
#include <hip/hip_runtime.h>
#include <hip/hip_bf16.h>

// ---------------------------------------------------------------------------
// Equivariant conv block. MFMA 32x32x16 implicit GEMM.
// R16 post-mortem: TWO B register sets (112 VGPR) + acc(64) + addr ~= 250 at
// the 256 budget -> allocator spilled B wholesale (VGPR=128, WRITE 3GB).
// Pipe model (counter-consistent): per CU per tap-pair LDS=1344cyc vs
// MFMA=896cyc -> LDS reads are the floor (67us of 106). R17: SINGLE B set
// (56 VGPR, total ~170 < 256): B(t) loaded to regs at tap start (L1/L2-hot,
// latency overlapped by same-tap ds_reads + co-resident block). LDS reads
// halve (28->14 per wave-tap) -> MFMA becomes floor (~46us). Barriers stay
// 2 per 7 taps (drains nearly free: only stale A-DMAs outstanding).
// Schedule identical to correctness-verified R15/R16.
// ---------------------------------------------------------------------------

using f4  = __attribute__((ext_vector_type(4)))  float;
using f16v= __attribute__((ext_vector_type(16))) float;
using s8  = __attribute__((ext_vector_type(8)))  short;  // 8 bf16

#define C_TOT 160
#define PZ_   37
#define NTAP  343
#define NROW  (4 * PZ_ * PZ_)   // 5476 (b,z,y) rows per chunk
#define KSN   8
#define SLICE_E 1048576         // bf16 elems per partial slice (4*64*4096)

// conv LDS: A-stripe only. Rows 1216 B data + 16 pad = 1232 stride, split by
// y'-parity: A_E = 19 rows (y'=0,2,..,36) at [0, 23552); A_O = 18 rows at
// [23552, 46080). Total 46080 (2 blocks/CU trivially).
// Epilogue reuses [0, 33792) as yb[64n][33 f4].
#define AROW    1232
#define AE_ROWS 19
#define AO_ROWS 18
#define AO_OFF  23552
#define LDS_SZ  46080

__device__ __forceinline__ void gl_lds16(const void* g, void* l) {
    __builtin_amdgcn_global_load_lds(
        (const __attribute__((address_space(1))) unsigned int*)g,
        (__attribute__((address_space(3))) unsigned int*)l, 16, 0, 0);
}

__device__ __forceinline__ void pair_ij(int p, int& i, int& j) {
    if (p < 3)      { i = p; j = p; }
    else if (p == 3){ i = 0; j = 1; }
    else if (p == 4){ i = 0; j = 2; }
    else            { i = 1; j = 2; }
}

struct bf2 { __hip_bfloat16 x, y; };
struct bh4 { __hip_bfloat16 x, y, z, w; };

// ---------------------------------------------------------------------------
// Merged prep: bid < 1372 -> build_w (tap = bid>>2, j-quarter), else build_xt.
// xt[chunk][brow][s][16ch], brow=(b*37+z)*37+y.  wl[chunk][tap][n][16ch].
// ---------------------------------------------------------------------------
__global__ void prep_kernel(
    const float* __restrict__ sv,
    const float* __restrict__ b_ss, const float* __restrict__ w_ss,
    const float* __restrict__ b_sv, const float* __restrict__ w_sv,
    const float* __restrict__ b_st, const float* __restrict__ w_st,
    const float* __restrict__ b_vs, const float* __restrict__ w_vs,
    const float* __restrict__ b_vv, const float* __restrict__ w_vv,
    const float* __restrict__ b_vt, const float* __restrict__ w_vt,
    __hip_bfloat16* __restrict__ xt, __hip_bfloat16* __restrict__ wl)
{
    __shared__ float S[13056];
    const int tid = threadIdx.x;

    if (blockIdx.x < 1372) {
        // ---------------- build_w ----------------
        float* L = S;           // 750
        float* W = S + 768;     // 12288
        const int tap = blockIdx.x >> 2;
        const int jq  = (blockIdx.x & 3) * 10;
        for (int r = tid; r < 750; r += 256) {
            float v;
            if (r < 3)        v = b_ss[r * NTAP + tap];
            else if (r < 12)  v = b_sv[(r - 3) * NTAP + tap];
            else if (r < 93)  v = b_st[(r - 12) * NTAP + tap];
            else if (r < 102) v = b_vs[(r - 93) * NTAP + tap];
            else if (r < 183) v = b_vv[(r - 102) * NTAP + tap];
            else              v = b_vt[(r - 183) * NTAP + tap];
            L[r] = v;
        }
        for (int r = tid; r < 12288; r += 256) {
            float v;
            if (r < 768)       v = w_ss[r];
            else if (r < 1536) v = w_sv[r - 768];
            else if (r < 3840) v = w_st[r - 1536];
            else if (r < 4608) v = w_vs[r - 3840];
            else if (r < 6912) v = w_vv[r - 4608];
            else               v = w_vt[r - 6912];
            W[r] = v;
        }
        __syncthreads();
        for (int j = jq; j < jq + 10; ++j) {
            const int idx = j * 256 + tid;
            const int c = idx % C_TOT, n = idx / C_TOT;
            float acc = 0.f;
            if (n < 16) {
                const int u = n;
                if (c < 16) {
                    for (int t = 0; t < 3; ++t) acc += W[(u*16 + c)*3 + t] * L[t];
                } else if (c < 64) {
                    int mm = (c-16)/3, di = (c-16)%3;
                    for (int t = 0; t < 3; ++t)
                        acc += W[768 + (u*16+mm)*3 + t] * L[3 + t*3 + di];
                } else {
                    int q = c-64, mm = q/6, p = q%6, i, jj;
                    pair_ij(p, i, jj);
                    int d1 = i*3+jj, d2 = jj*3+i;
                    for (int t = 0; t < 9; ++t) {
                        float bs = L[12 + t*9 + d1];
                        if (i != jj) bs += L[12 + t*9 + d2];
                        acc += W[1536 + (u*16+mm)*9 + t] * bs;
                    }
                }
            } else {
                const int u = (n-16)/3, dn = (n-16)%3;
                if (c < 16) {
                    for (int t = 0; t < 3; ++t)
                        acc += W[3840 + (u*16+c)*3 + t] * L[93 + t*3 + dn];
                } else if (c < 64) {
                    int mm = (c-16)/3, di = (c-16)%3;
                    for (int t = 0; t < 9; ++t)
                        acc += W[4608 + (u*16+mm)*9 + t] * L[102 + (t*3+dn)*3 + di];
                } else {
                    int q = c-64, mm = q/6, p = q%6, i, jj;
                    pair_ij(p, i, jj);
                    int d1 = i*3+jj, d2 = jj*3+i;
                    for (int t = 0; t < 21; ++t) {
                        float bs = L[183 + (t*3+dn)*9 + d1];
                        if (i != jj) bs += L[183 + (t*3+dn)*9 + d2];
                        acc += W[6912 + (u*16+mm)*21 + t] * bs;
                    }
                }
            }
            const int chunk = c >> 4, cw = c & 15;
            wl[((size_t)chunk * NTAP + tap) * 1024 + (size_t)n * 16 + cw] =
                __float2bfloat16(acc);
        }
    } else {
        // ---------------- build_xt ----------------
        float* row = S;                              // 32*66 = 2112
        const int bid = blockIdx.x - 1372;           // (b*37 + z)*37 + y
        const int y = bid % 37, z = (bid / 37) % 37, b = bid / 1369;
        const bool interior = (z >= 3 && z < 35 && y >= 3 && y < 35);
        if (interior) {
            const float* src = sv + (size_t)b * 2097152 + (z-3) * 1024 + (y-3) * 32;
            for (int f = tid; f < 2048; f += 256) {
                int ch = f >> 5, x = f & 31;
                row[x * 66 + ch] = src[(size_t)ch * 32768 + x];
            }
        }
        __syncthreads();
        for (int e2 = tid; e2 < 38 * 80; e2 += 256) {
            const int s = e2 / 80, cp = e2 % 80, c = cp * 2;
            float v0 = 0.f, v1 = 0.f;
            if (interior && s >= 3 && s < 35) {
                const int x = s - 3;
                if (c < 64) {
                    v0 = row[x * 66 + c];
                    v1 = row[x * 66 + c + 1];
                } else {
                    int q = c - 64, u = q / 6, p = q % 6, i, j;
                    pair_ij(p, i, j);
                    v0 = row[x * 66 + 16 + u * 3 + i] * row[x * 66 + 16 + u * 3 + j];
                    pair_ij(p + 1, i, j);
                    v1 = row[x * 66 + 16 + u * 3 + i] * row[x * 66 + 16 + u * 3 + j];
                }
            }
            bf2 w{__float2bfloat16(v0), __float2bfloat16(v1)};
            const int chunk = c >> 4, cw = c & 15;
            *(bf2*)(xt + ((size_t)chunk * NROW + bid) * 608 + s * 16 + cw) = w;
        }
    }
}

// ---------------------------------------------------------------------------
// Conv. Grid 512 (2 blocks/CU). Block = (b, oz, ks). K groups g=(chunk,kz) =
// ks..69 step 8; per group A-stripe (37 xt rows) staged once, parity split;
// taps ky = 1,3,5,0,2,4,6. Barriers ONLY at p==0 and p==3 (2 per 7 taps).
// B in a SINGLE named-register set, loaded per tap (L1/L2-hot).
// ---------------------------------------------------------------------------

#define B_DECL(P) s8 P##0, P##1, P##2, P##3, P##4, P##5, P##6, \
                     P##7, P##8, P##9, P##10, P##11, P##12, P##13

#define LOADB(P, g_, ky_) do {                                                \
    const int ch_ = (g_) / 7, kz_ = (g_) - ch_ * 7;                           \
    const __hip_bfloat16* wb_ = wlb                                           \
        + ((size_t)ch_ * NTAP + (size_t)(kz_ * 7 + (ky_)) * 7) * 1024;        \
    P##0  = *(const s8*)(wb_);          P##1  = *(const s8*)(wb_ + 512);      \
    P##2  = *(const s8*)(wb_ + 1024);   P##3  = *(const s8*)(wb_ + 1536);     \
    P##4  = *(const s8*)(wb_ + 2048);   P##5  = *(const s8*)(wb_ + 2560);     \
    P##6  = *(const s8*)(wb_ + 3072);   P##7  = *(const s8*)(wb_ + 3584);     \
    P##8  = *(const s8*)(wb_ + 4096);   P##9  = *(const s8*)(wb_ + 4608);     \
    P##10 = *(const s8*)(wb_ + 5120);   P##11 = *(const s8*)(wb_ + 5632);     \
    P##12 = *(const s8*)(wb_ + 6144);   P##13 = *(const s8*)(wb_ + 6656);     \
} while (0)

#define CSTEP(b0_, b1_, kx_) {                                                \
    const int s_   = sbase + (kx_);                                           \
    const int cgp_ = h ^ ((s_ >> 1) & 1);                                     \
    const char* ap_ = abp_ + s_ * 32 + cgp_ * 16;                             \
    const s8 a0_ = *(const s8*)(ap_);                                         \
    const s8 a1_ = *(const s8*)(ap_ + 8 * AROW);                              \
    acc[0][0] = __builtin_amdgcn_mfma_f32_32x32x16_bf16(a0_, b0_, acc[0][0], 0, 0, 0); \
    acc[0][1] = __builtin_amdgcn_mfma_f32_32x32x16_bf16(a0_, b1_, acc[0][1], 0, 0, 0); \
    acc[1][0] = __builtin_amdgcn_mfma_f32_32x32x16_bf16(a1_, b0_, acc[1][0], 0, 0, 0); \
    acc[1][1] = __builtin_amdgcn_mfma_f32_32x32x16_bf16(a1_, b1_, acc[1][1], 0, 0, 0); \
}

#define COMPT(P, ky_) do {                                                    \
    const char* abp_ = lds + (((ky_) & 1) ? AO_OFF : 0)                       \
                     + (rA0 + ((ky_) >> 1)) * AROW;                           \
    CSTEP(P##0,  P##1,  0) CSTEP(P##2,  P##3,  1) CSTEP(P##4,  P##5,  2)      \
    CSTEP(P##6,  P##7,  3) CSTEP(P##8,  P##9,  4) CSTEP(P##10, P##11, 5)      \
    CSTEP(P##12, P##13, 6)                                                    \
} while (0)

__global__ __launch_bounds__(256, 2) void conv_mfma_kernel(
    const __hip_bfloat16* __restrict__ xt,
    const __hip_bfloat16* __restrict__ wl,
    __hip_bfloat16* __restrict__ y4b)
{
    __shared__ __align__(16) char lds[LDS_SZ];

    // T1 XCD swizzle: grid = 512 = 8 XCDs x 64.
    const int phys = blockIdx.x;
    const int bid  = (phys & 7) * (64 * KSN / 8) + (phys >> 3);

    const int low3 = bid & 7;
    const int rest = bid >> 3;
    const int ks   = rest % KSN;
    const int mb   = (rest / KSN) * 8 + low3;   // 0..63
    const int b    = mb >> 4;                   // 0..3
    const int oz   = mb & 15;                   // z-out 0..15

    const int tid  = threadIdx.x;
    const int w    = tid >> 6;          // x-quarter
    const int lane = tid & 63;
    const int m    = lane & 31;
    const int h    = lane >> 5;         // k-half (8-ch group)

    // ---- per-lane invariant staging source offsets (elements) ----
    int invAE[6]; int nAE = 0;
#pragma unroll
    for (int k = 0; k < 6; ++k) {
        const int i = w + 4 * k;
        if (i < 23) {
            const int o = i * 1024 + lane * 16;
            int r = o / AROW;
            int rem = o - r * AROW;
            if (r > AE_ROWS - 1) { r = AE_ROWS - 1; rem = 0; }
            if (rem >= 1216) rem = 0;
            const int s  = rem >> 5;
            const int cg = ((rem >> 4) & 1) ^ ((s >> 1) & 1);
            invAE[k] = (2 * r) * 608 + s * 16 + cg * 8;      // y' = 2r
            nAE = k + 1;
        }
    }
    int invAO[6]; int nAO = 0;
#pragma unroll
    for (int k = 0; k < 6; ++k) {
        const int i = w + 4 * k;
        if (i < 22) {
            const int o = i * 1024 + lane * 16;
            int r = o / AROW;
            int rem = o - r * AROW;
            if (r > AO_ROWS - 1) { r = AO_ROWS - 1; rem = 0; }
            if (rem >= 1216) rem = 0;
            const int s  = rem >> 5;
            const int cg = ((rem >> 4) & 1) ^ ((s >> 1) & 1);
            invAO[k] = (2 * r + 1) * 608 + s * 16 + cg * 8;  // y' = 2r+1
            nAO = k + 1;
        }
    }

    const __hip_bfloat16* wlb = wl + (size_t)(m * 16 + h * 8);

    f16v acc[2][2];
    for (int t = 0; t < 2; ++t)
        for (int n = 0; n < 2; ++n)
            for (int k = 0; k < 16; ++k) acc[t][n][k] = 0.f;

    const int rA0   = ((m >> 4) << 2) + ((m >> 2) & 3);   // yo base 0..7
    const int sbase = (w << 3) + ((m & 3) << 1);          // + kx -> x slot

    auto stageAE = [&](int g) {
        const int chunk = g / 7, kz = g - chunk * 7;
        const size_t u = ((size_t)chunk * NROW
                        + (size_t)(b * PZ_ + 2 * oz + kz) * PZ_) * 608;
#pragma unroll
        for (int k = 0; k < 6; ++k)
            if (k < nAE) gl_lds16(xt + u + invAE[k], lds + (w + 4 * k) * 1024);
    };
    auto stageAO = [&](int g) {
        const int chunk = g / 7, kz = g - chunk * 7;
        const size_t u = ((size_t)chunk * NROW
                        + (size_t)(b * PZ_ + 2 * oz + kz) * PZ_) * 608;
#pragma unroll
        for (int k = 0; k < 6; ++k)
            if (k < nAO) gl_lds16(xt + u + invAO[k], lds + AO_OFF + (w + 4 * k) * 1024);
    };

    // ---- main loop ----
    const int G = (70 - ks + KSN - 1) / KSN;   // ks 0..5 -> 9, 6..7 -> 8
    const int T = G * 7;
    B_DECL(Ba);
    stageAO(ks);
    for (int t = 0; t < T; ++t) {
        const int gi = t / 7, p = t - gi * 7;
        const int g  = ks + gi * KSN;
        if (p == 0)      { __syncthreads(); stageAE(g); }
        else if (p == 3) { __syncthreads(); if (g + KSN < 70) stageAO(g + KSN); }
        const int ky = (p < 3) ? (2 * p + 1) : (2 * (p - 3));
        LOADB(Ba, g, ky);
        COMPT(Ba, ky);
    }

    // ---- epilogue: two-pass LDS transpose, coalesced bf16 partial stores ----
    // C/D 32x32: col(n)=lane&31, row m32=(reg&3)+8*(reg>>2)+4*h  [m74/m101]
    const int nl = lane & 31;
    f4* yb = (f4*)lds;                  // [64n][33 f4] padded = 33792 B
    __hip_bfloat16* dst0 = y4b + (size_t)ks * SLICE_E + (size_t)(b * 64) * 4096;
#pragma unroll
    for (int t = 0; t < 2; ++t) {       // yo-half
        __syncthreads();                // prior readers (or compute) done
#pragma unroll
        for (int nt = 0; nt < 2; ++nt) {
            const int n = nt * 32 + nl;
#pragma unroll
            for (int q = 0; q < 4; ++q) {
                const int rr = 2 * q + h;
                f4 v = { acc[t][nt][4*q], acc[t][nt][4*q+1],
                         acc[t][nt][4*q+2], acc[t][nt][4*q+3] };
                yb[n * 33 + rr * 4 + w] = v;
            }
        }
        __syncthreads();
        for (int j = tid; j < 2048; j += 256) {
            const int n  = j >> 5, sp = j & 31;    // sp = rr*4 + wq
            f4 v = yb[n * 33 + sp];
            const int rr = sp >> 2, wq = sp & 3;
            const int yo = t * 8 + (rr >> 2) * 4 + (rr & 3);
            bh4 p{__float2bfloat16(v.x), __float2bfloat16(v.y),
                  __float2bfloat16(v.z), __float2bfloat16(v.w)};
            *(bh4*)(dst0 + (size_t)n * 4096 + oz * 256 + yo * 16 + wq * 4) = p;
        }
    }
}

// ---------------------------------------------------------------------------
// Combine KSN bf16 partials -> f32 yc + per-(n,b) sum of squares. 256 blocks.
// ---------------------------------------------------------------------------
__global__ void combine_reduce_kernel(const __hip_bfloat16* __restrict__ y4b,
                                      float* __restrict__ yc,
                                      float* __restrict__ sums2)
{
    const int n = blockIdx.x & 63, q = blockIdx.x >> 6;
    const size_t base = ((size_t)q * 64 + n) * 4096;
    float s = 0.f;
    for (int i = threadIdx.x; i < 1024; i += 256) {
        const size_t off = base + (size_t)i * 4;
        f4 v = {0.f, 0.f, 0.f, 0.f};
#pragma unroll
        for (int k = 0; k < KSN; ++k) {
            bh4 r = *(const bh4*)(y4b + off + (size_t)k * SLICE_E);
            v.x += (float)r.x; v.y += (float)r.y;
            v.z += (float)r.z; v.w += (float)r.w;
        }
        *(f4*)(yc + off) = v;
        s += v.x * v.x + v.y * v.y + v.z * v.z + v.w * v.w;
    }
    __shared__ float red[256];
    red[threadIdx.x] = s;
    __syncthreads();
    for (int st = 128; st > 0; st >>= 1) {
        if (threadIdx.x < st) red[threadIdx.x] += red[threadIdx.x + st];
        __syncthreads();
    }
    if (threadIdx.x == 0) sums2[n * 4 + q] = red[0];
}

// ---------------------------------------------------------------------------
__global__ void finalize_kernel(const float* __restrict__ yc,
                                const float* __restrict__ sums2,
                                const float* __restrict__ g_s,
                                const float* __restrict__ g_v,
                                const float* __restrict__ bias_s,
                                float* __restrict__ out)
{
    const int idx = blockIdx.x * 256 + threadIdx.x;   // exact grid, 1M
    const int n = (idx >> 12) & 63;
    float v = yc[idx];
    if (n < 16) {
        float sum = sums2[n*4] + sums2[n*4+1] + sums2[n*4+2] + sums2[n*4+3];
        float var = sum * (1.0f / 16384.0f);
        float sc  = g_s[n] / sqrtf(var + 1e-5f);
        v = fmaxf(v * sc + bias_s[n], 0.f);
    } else {
        int u = (n - 16) / 3;
        float sum = 0.f;
        for (int k = 0; k < 12; ++k) sum += sums2[(16 + u * 3) * 4 + k];
        float var = sum * (1.0f / 49152.0f);
        v = v * (g_v[u] / sqrtf(var + 1e-5f));
    }
    out[idx] = v;
}

// ---------------------------------------------------------------------------
extern "C" void kernel_launch(void* const* d_in, const int* in_sizes, int n_in,
                              void* d_out, int out_size, void* d_ws, size_t ws_size,
                              hipStream_t stream)
{
    const float* sv    = (const float*)d_in[0];
    const float* b_ss  = (const float*)d_in[1];
    const float* w_ss  = (const float*)d_in[2];
    const float* b_sv  = (const float*)d_in[3];
    const float* w_sv  = (const float*)d_in[4];
    const float* b_st  = (const float*)d_in[5];
    const float* w_st  = (const float*)d_in[6];
    const float* b_vs  = (const float*)d_in[7];
    const float* w_vs  = (const float*)d_in[8];
    const float* b_vv  = (const float*)d_in[9];
    const float* w_vv  = (const float*)d_in[10];
    const float* b_vt  = (const float*)d_in[11];
    const float* w_vt  = (const float*)d_in[12];
    const float* bn_gs = (const float*)d_in[13];
    const float* bn_gv = (const float*)d_in[14];
    const float* bias_s= (const float*)d_in[15];
    float* out = (float*)d_out;

    char* ws = (char*)d_ws;
    constexpr size_t XT_BYTES = (size_t)10 * NROW * 1216;      // 66,588,160
    constexpr size_t WL_BYTES = (size_t)10 * NTAP * 2048;      //  7,024,640
    constexpr size_t Y4_BYTES = (size_t)KSN * SLICE_E * 2;     // 16,777,216
    constexpr size_t YC_BYTES = (size_t)4 * 64 * 4096 * 4;     //  4,194,304

    __hip_bfloat16* xt  = (__hip_bfloat16*)ws;
    __hip_bfloat16* wl  = (__hip_bfloat16*)(ws + XT_BYTES);
    __hip_bfloat16* y4b = (__hip_bfloat16*)(ws + XT_BYTES + WL_BYTES);
    float* yc    = (float*)(ws + XT_BYTES + WL_BYTES + Y4_BYTES);
    float* sums2 = (float*)(ws + XT_BYTES + WL_BYTES + Y4_BYTES + YC_BYTES);

    prep_kernel<<<1372 + 5476, 256, 0, stream>>>(
        sv, b_ss, w_ss, b_sv, w_sv, b_st, w_st, b_vs, w_vs, b_vv, w_vv,
        b_vt, w_vt, xt, wl);
    conv_mfma_kernel<<<64 * KSN, 256, 0, stream>>>(xt, wl, y4b);
    combine_reduce_kernel<<<256, 256, 0, stream>>>(y4b, yc, sums2);
    finalize_kernel<<<4096, 256, 0, stream>>>(yc, sums2, bn_gs, bn_gv, bias_s, out);
}

// Round 9
// 273.632 us; speedup vs baseline: 4.1798x; 1.1619x over previous
//
#include <hip/hip_runtime.h>
#include <hip/hip_bf16.h>

// ---------------------------------------------------------------------------
// Equivariant conv block. MFMA 32x32x16 implicit GEMM.
// R17 post-mortem: B-in-regs = 152us (per-tap L2 latency serialized; the old
// global_load_lds dbuf hid it). Conv reverted VERBATIM to R13 (105.6us best).
// R18 lever: the unexamined 168us of non-conv time. build_xt wrote 66.6MB as
// 16B-granule scattered stores (chunk-major every 8 lanes). Reindexed write
// loop: pair-index r within a (chunk,row) so consecutive lanes write
// CONTIGUOUS 4B -> 256B/wave coalesced stores (8x fewer transactions).
// Same values, same layout, pure iteration-order change.
// ---------------------------------------------------------------------------

using f4  = __attribute__((ext_vector_type(4)))  float;
using f16v= __attribute__((ext_vector_type(16))) float;
using s8  = __attribute__((ext_vector_type(8)))  short;  // 8 bf16

#define C_TOT 160
#define PZ_   37
#define NTAP  343
#define NROW  (4 * PZ_ * PZ_)   // 5476 (b,z,y) rows per chunk
#define KSN   8
#define SLICE_E 1048576         // bf16 elems per partial slice (4*64*4096)

// conv LDS: A-stripe rows (1216 B data + 16 pad = 1232 stride), split by
// y'-parity: A_E = 19 rows (y'=0,2,..,36) at [0, 23552); A_O = 18 rows at
// [23552, 46080). B at 46080: [kx7][nt2][cg2][n32][16B], dbuf 2x14336.
// Total 74752 B (x2 blocks/CU = 149504 <= 160KB).
// Epilogue reuses [0, 33792) as yb[64n][33 f4].
#define AROW    1232
#define AE_ROWS 19
#define AO_ROWS 18
#define AO_OFF  23552
#define B_OFF   46080
#define BSZ     14336
#define LDS_SZ  (B_OFF + 2 * BSZ)   // 74752

__device__ __forceinline__ void gl_lds16(const void* g, void* l) {
    __builtin_amdgcn_global_load_lds(
        (const __attribute__((address_space(1))) unsigned int*)g,
        (__attribute__((address_space(3))) unsigned int*)l, 16, 0, 0);
}

__device__ __forceinline__ void pair_ij(int p, int& i, int& j) {
    if (p < 3)      { i = p; j = p; }
    else if (p == 3){ i = 0; j = 1; }
    else if (p == 4){ i = 0; j = 2; }
    else            { i = 1; j = 2; }
}

struct bf2 { __hip_bfloat16 x, y; };
struct bh4 { __hip_bfloat16 x, y, z, w; };

// ---------------------------------------------------------------------------
// Merged prep: bid < 1372 -> build_w (tap = bid>>2, j-quarter), else build_xt.
// xt[chunk][brow][s][16ch], brow=(b*37+z)*37+y.  wl[chunk][tap][n][16ch].
// ---------------------------------------------------------------------------
__global__ void prep_kernel(
    const float* __restrict__ sv,
    const float* __restrict__ b_ss, const float* __restrict__ w_ss,
    const float* __restrict__ b_sv, const float* __restrict__ w_sv,
    const float* __restrict__ b_st, const float* __restrict__ w_st,
    const float* __restrict__ b_vs, const float* __restrict__ w_vs,
    const float* __restrict__ b_vv, const float* __restrict__ w_vv,
    const float* __restrict__ b_vt, const float* __restrict__ w_vt,
    __hip_bfloat16* __restrict__ xt, __hip_bfloat16* __restrict__ wl)
{
    __shared__ float S[13056];
    const int tid = threadIdx.x;

    if (blockIdx.x < 1372) {
        // ---------------- build_w ----------------
        float* L = S;           // 750
        float* W = S + 768;     // 12288
        const int tap = blockIdx.x >> 2;
        const int jq  = (blockIdx.x & 3) * 10;
        for (int r = tid; r < 750; r += 256) {
            float v;
            if (r < 3)        v = b_ss[r * NTAP + tap];
            else if (r < 12)  v = b_sv[(r - 3) * NTAP + tap];
            else if (r < 93)  v = b_st[(r - 12) * NTAP + tap];
            else if (r < 102) v = b_vs[(r - 93) * NTAP + tap];
            else if (r < 183) v = b_vv[(r - 102) * NTAP + tap];
            else              v = b_vt[(r - 183) * NTAP + tap];
            L[r] = v;
        }
        for (int r = tid; r < 12288; r += 256) {
            float v;
            if (r < 768)       v = w_ss[r];
            else if (r < 1536) v = w_sv[r - 768];
            else if (r < 3840) v = w_st[r - 1536];
            else if (r < 4608) v = w_vs[r - 3840];
            else if (r < 6912) v = w_vv[r - 4608];
            else               v = w_vt[r - 6912];
            W[r] = v;
        }
        __syncthreads();
        for (int j = jq; j < jq + 10; ++j) {
            const int idx = j * 256 + tid;
            const int c = idx % C_TOT, n = idx / C_TOT;
            float acc = 0.f;
            if (n < 16) {
                const int u = n;
                if (c < 16) {
                    for (int t = 0; t < 3; ++t) acc += W[(u*16 + c)*3 + t] * L[t];
                } else if (c < 64) {
                    int mm = (c-16)/3, di = (c-16)%3;
                    for (int t = 0; t < 3; ++t)
                        acc += W[768 + (u*16+mm)*3 + t] * L[3 + t*3 + di];
                } else {
                    int q = c-64, mm = q/6, p = q%6, i, jj;
                    pair_ij(p, i, jj);
                    int d1 = i*3+jj, d2 = jj*3+i;
                    for (int t = 0; t < 9; ++t) {
                        float bs = L[12 + t*9 + d1];
                        if (i != jj) bs += L[12 + t*9 + d2];
                        acc += W[1536 + (u*16+mm)*9 + t] * bs;
                    }
                }
            } else {
                const int u = (n-16)/3, dn = (n-16)%3;
                if (c < 16) {
                    for (int t = 0; t < 3; ++t)
                        acc += W[3840 + (u*16+c)*3 + t] * L[93 + t*3 + dn];
                } else if (c < 64) {
                    int mm = (c-16)/3, di = (c-16)%3;
                    for (int t = 0; t < 9; ++t)
                        acc += W[4608 + (u*16+mm)*9 + t] * L[102 + (t*3+dn)*3 + di];
                } else {
                    int q = c-64, mm = q/6, p = q%6, i, jj;
                    pair_ij(p, i, jj);
                    int d1 = i*3+jj, d2 = jj*3+i;
                    for (int t = 0; t < 21; ++t) {
                        float bs = L[183 + (t*3+dn)*9 + d1];
                        if (i != jj) bs += L[183 + (t*3+dn)*9 + d2];
                        acc += W[6912 + (u*16+mm)*21 + t] * bs;
                    }
                }
            }
            const int chunk = c >> 4, cw = c & 15;
            wl[((size_t)chunk * NTAP + tap) * 1024 + (size_t)n * 16 + cw] =
                __float2bfloat16(acc);
        }
    } else {
        // ---------------- build_xt ----------------
        float* row = S;                              // 32*66 = 2112
        const int bid = blockIdx.x - 1372;           // (b*37 + z)*37 + y
        const int y = bid % 37, z = (bid / 37) % 37, b = bid / 1369;
        const bool interior = (z >= 3 && z < 35 && y >= 3 && y < 35);
        if (interior) {
            const float* src = sv + (size_t)b * 2097152 + (z-3) * 1024 + (y-3) * 32;
            for (int f = tid; f < 2048; f += 256) {
                int ch = f >> 5, x = f & 31;
                row[x * 66 + ch] = src[(size_t)ch * 32768 + x];
            }
        }
        __syncthreads();
        // R18: coalesced writes — pair-index r within (chunk,row): consecutive
        // lanes write contiguous 4B (256B/wave). Same values/layout as before.
        for (int e2 = tid; e2 < 3040; e2 += 256) {
            const int chunk = e2 / 304;              // 0..9
            const int r     = e2 - chunk * 304;      // 0..303 (elem-pair idx)
            const int s     = r >> 3;                // 0..37
            const int cw    = (r & 7) * 2;
            const int c     = chunk * 16 + cw;
            float v0 = 0.f, v1 = 0.f;
            if (interior && s >= 3 && s < 35) {
                const int x = s - 3;
                if (c < 64) {
                    v0 = row[x * 66 + c];
                    v1 = row[x * 66 + c + 1];
                } else {
                    int q = c - 64, u = q / 6, p = q % 6, i, j;
                    pair_ij(p, i, j);
                    v0 = row[x * 66 + 16 + u * 3 + i] * row[x * 66 + 16 + u * 3 + j];
                    pair_ij(p + 1, i, j);
                    v1 = row[x * 66 + 16 + u * 3 + i] * row[x * 66 + 16 + u * 3 + j];
                }
            }
            bf2 w{__float2bfloat16(v0), __float2bfloat16(v1)};
            *(bf2*)(xt + ((size_t)chunk * NROW + bid) * 608 + r * 2) = w;
        }
    }
}

// ---------------------------------------------------------------------------
// Conv (R13 verbatim, verified 105.6us). Grid 512 (2 blocks/CU). Block =
// (b, oz, ks). K groups g=(chunk,kz) = ks..69 step 8; per group A-stripe
// (37 xt rows) staged once, parity split; taps ky = 1,3,5,0,2,4,6.
// B staged per tap (LDS dbuf). One barrier per tap.
// ---------------------------------------------------------------------------
__global__ __launch_bounds__(256, 2) void conv_mfma_kernel(
    const __hip_bfloat16* __restrict__ xt,
    const __hip_bfloat16* __restrict__ wl,
    __hip_bfloat16* __restrict__ y4b)
{
    __shared__ __align__(16) char lds[LDS_SZ];

    // T1 XCD swizzle: grid = 512 = 8 XCDs x 64.
    const int phys = blockIdx.x;
    const int bid  = (phys & 7) * (64 * KSN / 8) + (phys >> 3);

    const int low3 = bid & 7;
    const int rest = bid >> 3;
    const int ks   = rest % KSN;
    const int mb   = (rest / KSN) * 8 + low3;   // 0..63
    const int b    = mb >> 4;                   // 0..3
    const int oz   = mb & 15;                   // z-out 0..15

    const int tid  = threadIdx.x;
    const int w    = tid >> 6;          // x-quarter
    const int lane = tid & 63;
    const int m    = lane & 31;
    const int h    = lane >> 5;         // k-half (8-ch group)

    // ---- per-lane invariant staging source offsets (elements) ----
    int invAE[6]; int nAE = 0;
#pragma unroll
    for (int k = 0; k < 6; ++k) {
        const int i = w + 4 * k;
        if (i < 23) {
            const int o = i * 1024 + lane * 16;
            int r = o / AROW;
            int rem = o - r * AROW;
            if (r > AE_ROWS - 1) { r = AE_ROWS - 1; rem = 0; }
            if (rem >= 1216) rem = 0;
            const int s  = rem >> 5;
            const int cg = ((rem >> 4) & 1) ^ ((s >> 1) & 1);
            invAE[k] = (2 * r) * 608 + s * 16 + cg * 8;      // y' = 2r
            nAE = k + 1;
        }
    }
    int invAO[6]; int nAO = 0;
#pragma unroll
    for (int k = 0; k < 6; ++k) {
        const int i = w + 4 * k;
        if (i < 22) {
            const int o = i * 1024 + lane * 16;
            int r = o / AROW;
            int rem = o - r * AROW;
            if (r > AO_ROWS - 1) { r = AO_ROWS - 1; rem = 0; }
            if (rem >= 1216) rem = 0;
            const int s  = rem >> 5;
            const int cg = ((rem >> 4) & 1) ^ ((s >> 1) & 1);
            invAO[k] = (2 * r + 1) * 608 + s * 16 + cg * 8;  // y' = 2r+1
            nAO = k + 1;
        }
    }
    int invB[4]; int nB = 0;
#pragma unroll
    for (int k = 0; k < 4; ++k) {
        const int i = w + 4 * k;
        if (i < 14) {
            const int kx = i >> 1, nt = i & 1;
            invB[k] = kx * 1024 + (nt * 32 + m) * 16 + h * 8;
            nB = k + 1;
        }
    }

    f16v acc[2][2];
    for (int t = 0; t < 2; ++t)
        for (int n = 0; n < 2; ++n)
            for (int k = 0; k < 16; ++k) acc[t][n][k] = 0.f;

    const int rA0   = ((m >> 4) << 2) + ((m >> 2) & 3);   // yo base 0..7
    const int sbase = (w << 3) + ((m & 3) << 1);          // + kx -> x slot

    auto stageAE = [&](int g) {
        const int chunk = g / 7, kz = g - chunk * 7;
        const size_t u = ((size_t)chunk * NROW
                        + (size_t)(b * PZ_ + 2 * oz + kz) * PZ_) * 608;
#pragma unroll
        for (int k = 0; k < 6; ++k)
            if (k < nAE) gl_lds16(xt + u + invAE[k], lds + (w + 4 * k) * 1024);
    };
    auto stageAO = [&](int g) {
        const int chunk = g / 7, kz = g - chunk * 7;
        const size_t u = ((size_t)chunk * NROW
                        + (size_t)(b * PZ_ + 2 * oz + kz) * PZ_) * 608;
#pragma unroll
        for (int k = 0; k < 6; ++k)
            if (k < nAO) gl_lds16(xt + u + invAO[k], lds + AO_OFF + (w + 4 * k) * 1024);
    };
    auto stageB = [&](int g, int kyv, int bsel) {
        const int chunk = g / 7, kz = g - chunk * 7;
        const size_t u = ((size_t)chunk * NTAP + (size_t)(kz * 7 + kyv) * 7) * 1024;
        char* dst = lds + B_OFF + bsel * BSZ;
#pragma unroll
        for (int k = 0; k < 4; ++k)
            if (k < nB) gl_lds16(wl + u + invB[k], dst + (w + 4 * k) * 1024);
    };

    auto compute = [&](int ky, int bsel) {
        const int abase = (ky & 1) ? AO_OFF : 0;
        const char* abp = lds + abase + (rA0 + (ky >> 1)) * AROW;
        const char* bbp = lds + B_OFF + bsel * BSZ;
#pragma unroll
        for (int kx = 0; kx < 7; ++kx) {
            const int s   = sbase + kx;
            const int cgp = h ^ ((s >> 1) & 1);
            const char* ap = abp + s * 32 + cgp * 16;
            const s8 a0 = *(const s8*)(ap);
            const s8 a1 = *(const s8*)(ap + 8 * AROW);
            const char* bp = bbp + kx * 2048 + h * 512 + m * 16;
            const s8 b0 = *(const s8*)(bp);
            const s8 b1 = *(const s8*)(bp + 1024);
            acc[0][0] = __builtin_amdgcn_mfma_f32_32x32x16_bf16(a0, b0, acc[0][0], 0, 0, 0);
            acc[0][1] = __builtin_amdgcn_mfma_f32_32x32x16_bf16(a0, b1, acc[0][1], 0, 0, 0);
            acc[1][0] = __builtin_amdgcn_mfma_f32_32x32x16_bf16(a1, b0, acc[1][0], 0, 0, 0);
            acc[1][1] = __builtin_amdgcn_mfma_f32_32x32x16_bf16(a1, b1, acc[1][1], 0, 0, 0);
        }
    };

    // ---- main loop: groups g = ks..69 step 8; taps ky order 1,3,5,0,2,4,6 ----
    const int G = (70 - ks + KSN - 1) / KSN;   // ks 0..5 -> 9, 6..7 -> 8
    const int T = G * 7;
    stageAO(ks);
    stageB(ks, 1, 0);
    __syncthreads();
    int bB = 0;
    for (int t = 0; t < T; ++t) {
        const int gi = t / 7, p = t - gi * 7;
        const int g  = ks + gi * KSN;
        const int ky = (p < 3) ? (2 * p + 1) : (2 * (p - 3));
        const int tn = t + 1;
        if (tn < T) {
            const int gin = tn / 7, pn = tn - gin * 7;
            const int kyn = (pn < 3) ? (2 * pn + 1) : (2 * (pn - 3));
            stageB(ks + gin * KSN, kyn, bB ^ 1);
        }
        if (p == 0) stageAE(g);                        // compute reads A_O
        else if (p == 3 && g + KSN < 70) stageAO(g + KSN);  // compute reads A_E
        compute(ky, bB);
        __syncthreads();                               // drains lds-DMA
        bB ^= 1;
    }

    // ---- epilogue: two-pass LDS transpose, coalesced bf16 partial stores ----
    // C/D 32x32: col(n)=lane&31, row m32=(reg&3)+8*(reg>>2)+4*h  [m74/m101]
    const int nl = lane & 31;
    f4* yb = (f4*)lds;                  // [64n][33 f4] padded = 33792 B
    __hip_bfloat16* dst0 = y4b + (size_t)ks * SLICE_E + (size_t)(b * 64) * 4096;
#pragma unroll
    for (int t = 0; t < 2; ++t) {       // yo-half
        __syncthreads();                // prior readers (or compute) done
#pragma unroll
        for (int nt = 0; nt < 2; ++nt) {
            const int n = nt * 32 + nl;
#pragma unroll
            for (int q = 0; q < 4; ++q) {
                const int rr = 2 * q + h;
                f4 v = { acc[t][nt][4*q], acc[t][nt][4*q+1],
                         acc[t][nt][4*q+2], acc[t][nt][4*q+3] };
                yb[n * 33 + rr * 4 + w] = v;
            }
        }
        __syncthreads();
        for (int j = tid; j < 2048; j += 256) {
            const int n  = j >> 5, sp = j & 31;    // sp = rr*4 + wq
            f4 v = yb[n * 33 + sp];
            const int rr = sp >> 2, wq = sp & 3;
            const int yo = t * 8 + (rr >> 2) * 4 + (rr & 3);
            bh4 p{__float2bfloat16(v.x), __float2bfloat16(v.y),
                  __float2bfloat16(v.z), __float2bfloat16(v.w)};
            *(bh4*)(dst0 + (size_t)n * 4096 + oz * 256 + yo * 16 + wq * 4) = p;
        }
    }
}

// ---------------------------------------------------------------------------
// Combine KSN bf16 partials -> f32 yc + per-(n,b) sum of squares. 256 blocks.
// ---------------------------------------------------------------------------
__global__ void combine_reduce_kernel(const __hip_bfloat16* __restrict__ y4b,
                                      float* __restrict__ yc,
                                      float* __restrict__ sums2)
{
    const int n = blockIdx.x & 63, q = blockIdx.x >> 6;
    const size_t base = ((size_t)q * 64 + n) * 4096;
    float s = 0.f;
    for (int i = threadIdx.x; i < 1024; i += 256) {
        const size_t off = base + (size_t)i * 4;
        f4 v = {0.f, 0.f, 0.f, 0.f};
#pragma unroll
        for (int k = 0; k < KSN; ++k) {
            bh4 r = *(const bh4*)(y4b + off + (size_t)k * SLICE_E);
            v.x += (float)r.x; v.y += (float)r.y;
            v.z += (float)r.z; v.w += (float)r.w;
        }
        *(f4*)(yc + off) = v;
        s += v.x * v.x + v.y * v.y + v.z * v.z + v.w * v.w;
    }
    __shared__ float red[256];
    red[threadIdx.x] = s;
    __syncthreads();
    for (int st = 128; st > 0; st >>= 1) {
        if (threadIdx.x < st) red[threadIdx.x] += red[threadIdx.x + st];
        __syncthreads();
    }
    if (threadIdx.x == 0) sums2[n * 4 + q] = red[0];
}

// ---------------------------------------------------------------------------
__global__ void finalize_kernel(const float* __restrict__ yc,
                                const float* __restrict__ sums2,
                                const float* __restrict__ g_s,
                                const float* __restrict__ g_v,
                                const float* __restrict__ bias_s,
                                float* __restrict__ out)
{
    const int idx = blockIdx.x * 256 + threadIdx.x;   // exact grid, 1M
    const int n = (idx >> 12) & 63;
    float v = yc[idx];
    if (n < 16) {
        float sum = sums2[n*4] + sums2[n*4+1] + sums2[n*4+2] + sums2[n*4+3];
        float var = sum * (1.0f / 16384.0f);
        float sc  = g_s[n] / sqrtf(var + 1e-5f);
        v = fmaxf(v * sc + bias_s[n], 0.f);
    } else {
        int u = (n - 16) / 3;
        float sum = 0.f;
        for (int k = 0; k < 12; ++k) sum += sums2[(16 + u * 3) * 4 + k];
        float var = sum * (1.0f / 49152.0f);
        v = v * (g_v[u] / sqrtf(var + 1e-5f));
    }
    out[idx] = v;
}

// ---------------------------------------------------------------------------
extern "C" void kernel_launch(void* const* d_in, const int* in_sizes, int n_in,
                              void* d_out, int out_size, void* d_ws, size_t ws_size,
                              hipStream_t stream)
{
    const float* sv    = (const float*)d_in[0];
    const float* b_ss  = (const float*)d_in[1];
    const float* w_ss  = (const float*)d_in[2];
    const float* b_sv  = (const float*)d_in[3];
    const float* w_sv  = (const float*)d_in[4];
    const float* b_st  = (const float*)d_in[5];
    const float* w_st  = (const float*)d_in[6];
    const float* b_vs  = (const float*)d_in[7];
    const float* w_vs  = (const float*)d_in[8];
    const float* b_vv  = (const float*)d_in[9];
    const float* w_vv  = (const float*)d_in[10];
    const float* b_vt  = (const float*)d_in[11];
    const float* w_vt  = (const float*)d_in[12];
    const float* bn_gs = (const float*)d_in[13];
    const float* bn_gv = (const float*)d_in[14];
    const float* bias_s= (const float*)d_in[15];
    float* out = (float*)d_out;

    char* ws = (char*)d_ws;
    constexpr size_t XT_BYTES = (size_t)10 * NROW * 1216;      // 66,588,160
    constexpr size_t WL_BYTES = (size_t)10 * NTAP * 2048;      //  7,024,640
    constexpr size_t Y4_BYTES = (size_t)KSN * SLICE_E * 2;     // 16,777,216
    constexpr size_t YC_BYTES = (size_t)4 * 64 * 4096 * 4;     //  4,194,304

    __hip_bfloat16* xt  = (__hip_bfloat16*)ws;
    __hip_bfloat16* wl  = (__hip_bfloat16*)(ws + XT_BYTES);
    __hip_bfloat16* y4b = (__hip_bfloat16*)(ws + XT_BYTES + WL_BYTES);
    float* yc    = (float*)(ws + XT_BYTES + WL_BYTES + Y4_BYTES);
    float* sums2 = (float*)(ws + XT_BYTES + WL_BYTES + Y4_BYTES + YC_BYTES);

    prep_kernel<<<1372 + 5476, 256, 0, stream>>>(
        sv, b_ss, w_ss, b_sv, w_sv, b_st, w_st, b_vs, w_vs, b_vv, w_vv,
        b_vt, w_vt, xt, wl);
    conv_mfma_kernel<<<64 * KSN, 256, 0, stream>>>(xt, wl, y4b);
    combine_reduce_kernel<<<256, 256, 0, stream>>>(y4b, yc, sums2);
    finalize_kernel<<<4096, 256, 0, stream>>>(yc, sums2, bn_gs, bn_gv, bias_s, out);
}

// Round 10
// 272.865 us; speedup vs baseline: 4.1916x; 1.0028x over previous
//
#include <hip/hip_runtime.h>
#include <hip/hip_bf16.h>

// ---------------------------------------------------------------------------
// Equivariant conv block. MFMA 32x32x16 implicit GEMM.
// R18 post-mortem: coalesced xt writes = no change (273.6); conv plateau 107
// reconfirmed. The hidden non-conv ~166us: merged prep declared S[13056] =
// 52KB shared, LDS-capping ALL 6848 blocks (incl. 5476 build_xt blocks that
// need only 8.4KB) to 3 blocks/CU. R19: SPLIT prep -> build_w (52KB, 1372
// blocks) + build_xt (8.4KB, 5476 blocks -> 8 blocks/CU, 2.7x latency
// hiding). Bodies byte-identical; conv/combine/finalize = verified R18.
// ---------------------------------------------------------------------------

using f4  = __attribute__((ext_vector_type(4)))  float;
using f16v= __attribute__((ext_vector_type(16))) float;
using s8  = __attribute__((ext_vector_type(8)))  short;  // 8 bf16

#define C_TOT 160
#define PZ_   37
#define NTAP  343
#define NROW  (4 * PZ_ * PZ_)   // 5476 (b,z,y) rows per chunk
#define KSN   8
#define SLICE_E 1048576         // bf16 elems per partial slice (4*64*4096)

// conv LDS: A-stripe rows (1216 B data + 16 pad = 1232 stride), split by
// y'-parity: A_E = 19 rows (y'=0,2,..,36) at [0, 23552); A_O = 18 rows at
// [23552, 46080). B at 46080: [kx7][nt2][cg2][n32][16B], dbuf 2x14336.
// Total 74752 B (x2 blocks/CU = 149504 <= 160KB).
// Epilogue reuses [0, 33792) as yb[64n][33 f4].
#define AROW    1232
#define AE_ROWS 19
#define AO_ROWS 18
#define AO_OFF  23552
#define B_OFF   46080
#define BSZ     14336
#define LDS_SZ  (B_OFF + 2 * BSZ)   // 74752

__device__ __forceinline__ void gl_lds16(const void* g, void* l) {
    __builtin_amdgcn_global_load_lds(
        (const __attribute__((address_space(1))) unsigned int*)g,
        (__attribute__((address_space(3))) unsigned int*)l, 16, 0, 0);
}

__device__ __forceinline__ void pair_ij(int p, int& i, int& j) {
    if (p < 3)      { i = p; j = p; }
    else if (p == 3){ i = 0; j = 1; }
    else if (p == 4){ i = 0; j = 2; }
    else            { i = 1; j = 2; }
}

struct bf2 { __hip_bfloat16 x, y; };
struct bh4 { __hip_bfloat16 x, y, z, w; };

// ---------------------------------------------------------------------------
// build_w: tap = bid>>2, j-quarter = bid&3. wl[chunk][tap][n][16ch].
// ---------------------------------------------------------------------------
__global__ void build_w_kernel(
    const float* __restrict__ b_ss, const float* __restrict__ w_ss,
    const float* __restrict__ b_sv, const float* __restrict__ w_sv,
    const float* __restrict__ b_st, const float* __restrict__ w_st,
    const float* __restrict__ b_vs, const float* __restrict__ w_vs,
    const float* __restrict__ b_vv, const float* __restrict__ w_vv,
    const float* __restrict__ b_vt, const float* __restrict__ w_vt,
    __hip_bfloat16* __restrict__ wl)
{
    __shared__ float S[13056];
    const int tid = threadIdx.x;
    float* L = S;           // 750
    float* W = S + 768;     // 12288
    const int tap = blockIdx.x >> 2;
    const int jq  = (blockIdx.x & 3) * 10;
    for (int r = tid; r < 750; r += 256) {
        float v;
        if (r < 3)        v = b_ss[r * NTAP + tap];
        else if (r < 12)  v = b_sv[(r - 3) * NTAP + tap];
        else if (r < 93)  v = b_st[(r - 12) * NTAP + tap];
        else if (r < 102) v = b_vs[(r - 93) * NTAP + tap];
        else if (r < 183) v = b_vv[(r - 102) * NTAP + tap];
        else              v = b_vt[(r - 183) * NTAP + tap];
        L[r] = v;
    }
    for (int r = tid; r < 12288; r += 256) {
        float v;
        if (r < 768)       v = w_ss[r];
        else if (r < 1536) v = w_sv[r - 768];
        else if (r < 3840) v = w_st[r - 1536];
        else if (r < 4608) v = w_vs[r - 3840];
        else if (r < 6912) v = w_vv[r - 4608];
        else               v = w_vt[r - 6912];
        W[r] = v;
    }
    __syncthreads();
    for (int j = jq; j < jq + 10; ++j) {
        const int idx = j * 256 + tid;
        const int c = idx % C_TOT, n = idx / C_TOT;
        float acc = 0.f;
        if (n < 16) {
            const int u = n;
            if (c < 16) {
                for (int t = 0; t < 3; ++t) acc += W[(u*16 + c)*3 + t] * L[t];
            } else if (c < 64) {
                int mm = (c-16)/3, di = (c-16)%3;
                for (int t = 0; t < 3; ++t)
                    acc += W[768 + (u*16+mm)*3 + t] * L[3 + t*3 + di];
            } else {
                int q = c-64, mm = q/6, p = q%6, i, jj;
                pair_ij(p, i, jj);
                int d1 = i*3+jj, d2 = jj*3+i;
                for (int t = 0; t < 9; ++t) {
                    float bs = L[12 + t*9 + d1];
                    if (i != jj) bs += L[12 + t*9 + d2];
                    acc += W[1536 + (u*16+mm)*9 + t] * bs;
                }
            }
        } else {
            const int u = (n-16)/3, dn = (n-16)%3;
            if (c < 16) {
                for (int t = 0; t < 3; ++t)
                    acc += W[3840 + (u*16+c)*3 + t] * L[93 + t*3 + dn];
            } else if (c < 64) {
                int mm = (c-16)/3, di = (c-16)%3;
                for (int t = 0; t < 9; ++t)
                    acc += W[4608 + (u*16+mm)*9 + t] * L[102 + (t*3+dn)*3 + di];
            } else {
                int q = c-64, mm = q/6, p = q%6, i, jj;
                pair_ij(p, i, jj);
                int d1 = i*3+jj, d2 = jj*3+i;
                for (int t = 0; t < 21; ++t) {
                    float bs = L[183 + (t*3+dn)*9 + d1];
                    if (i != jj) bs += L[183 + (t*3+dn)*9 + d2];
                    acc += W[6912 + (u*16+mm)*21 + t] * bs;
                }
            }
        }
        const int chunk = c >> 4, cw = c & 15;
        wl[((size_t)chunk * NTAP + tap) * 1024 + (size_t)n * 16 + cw] =
            __float2bfloat16(acc);
    }
}

// ---------------------------------------------------------------------------
// build_xt: bid = (b*37 + z)*37 + y. xt[chunk][brow][s][16ch].
// Small shared (8448 B) -> 8 blocks/CU (wave-capped).
// ---------------------------------------------------------------------------
__global__ void build_xt_kernel(
    const float* __restrict__ sv, __hip_bfloat16* __restrict__ xt)
{
    __shared__ float row[2112];                  // 32*66
    const int tid = threadIdx.x;
    const int bid = blockIdx.x;                  // (b*37 + z)*37 + y
    const int y = bid % 37, z = (bid / 37) % 37, b = bid / 1369;
    const bool interior = (z >= 3 && z < 35 && y >= 3 && y < 35);
    if (interior) {
        const float* src = sv + (size_t)b * 2097152 + (z-3) * 1024 + (y-3) * 32;
        for (int f = tid; f < 2048; f += 256) {
            int ch = f >> 5, x = f & 31;
            row[x * 66 + ch] = src[(size_t)ch * 32768 + x];
        }
    }
    __syncthreads();
    // Coalesced writes: pair-index r within (chunk,row) — consecutive lanes
    // write contiguous 4B (256B/wave).
    for (int e2 = tid; e2 < 3040; e2 += 256) {
        const int chunk = e2 / 304;              // 0..9
        const int r     = e2 - chunk * 304;      // 0..303 (elem-pair idx)
        const int s     = r >> 3;                // 0..37
        const int cw    = (r & 7) * 2;
        const int c     = chunk * 16 + cw;
        float v0 = 0.f, v1 = 0.f;
        if (interior && s >= 3 && s < 35) {
            const int x = s - 3;
            if (c < 64) {
                v0 = row[x * 66 + c];
                v1 = row[x * 66 + c + 1];
            } else {
                int q = c - 64, u = q / 6, p = q % 6, i, j;
                pair_ij(p, i, j);
                v0 = row[x * 66 + 16 + u * 3 + i] * row[x * 66 + 16 + u * 3 + j];
                pair_ij(p + 1, i, j);
                v1 = row[x * 66 + 16 + u * 3 + i] * row[x * 66 + 16 + u * 3 + j];
            }
        }
        bf2 w{__float2bfloat16(v0), __float2bfloat16(v1)};
        *(bf2*)(xt + ((size_t)chunk * NROW + bid) * 608 + r * 2) = w;
    }
}

// ---------------------------------------------------------------------------
// Conv (R13 verbatim, verified ~107us). Grid 512 (2 blocks/CU). Block =
// (b, oz, ks). K groups g=(chunk,kz) = ks..69 step 8; per group A-stripe
// (37 xt rows) staged once, parity split; taps ky = 1,3,5,0,2,4,6.
// B staged per tap (LDS dbuf). One barrier per tap.
// ---------------------------------------------------------------------------
__global__ __launch_bounds__(256, 2) void conv_mfma_kernel(
    const __hip_bfloat16* __restrict__ xt,
    const __hip_bfloat16* __restrict__ wl,
    __hip_bfloat16* __restrict__ y4b)
{
    __shared__ __align__(16) char lds[LDS_SZ];

    // T1 XCD swizzle: grid = 512 = 8 XCDs x 64.
    const int phys = blockIdx.x;
    const int bid  = (phys & 7) * (64 * KSN / 8) + (phys >> 3);

    const int low3 = bid & 7;
    const int rest = bid >> 3;
    const int ks   = rest % KSN;
    const int mb   = (rest / KSN) * 8 + low3;   // 0..63
    const int b    = mb >> 4;                   // 0..3
    const int oz   = mb & 15;                   // z-out 0..15

    const int tid  = threadIdx.x;
    const int w    = tid >> 6;          // x-quarter
    const int lane = tid & 63;
    const int m    = lane & 31;
    const int h    = lane >> 5;         // k-half (8-ch group)

    // ---- per-lane invariant staging source offsets (elements) ----
    int invAE[6]; int nAE = 0;
#pragma unroll
    for (int k = 0; k < 6; ++k) {
        const int i = w + 4 * k;
        if (i < 23) {
            const int o = i * 1024 + lane * 16;
            int r = o / AROW;
            int rem = o - r * AROW;
            if (r > AE_ROWS - 1) { r = AE_ROWS - 1; rem = 0; }
            if (rem >= 1216) rem = 0;
            const int s  = rem >> 5;
            const int cg = ((rem >> 4) & 1) ^ ((s >> 1) & 1);
            invAE[k] = (2 * r) * 608 + s * 16 + cg * 8;      // y' = 2r
            nAE = k + 1;
        }
    }
    int invAO[6]; int nAO = 0;
#pragma unroll
    for (int k = 0; k < 6; ++k) {
        const int i = w + 4 * k;
        if (i < 22) {
            const int o = i * 1024 + lane * 16;
            int r = o / AROW;
            int rem = o - r * AROW;
            if (r > AO_ROWS - 1) { r = AO_ROWS - 1; rem = 0; }
            if (rem >= 1216) rem = 0;
            const int s  = rem >> 5;
            const int cg = ((rem >> 4) & 1) ^ ((s >> 1) & 1);
            invAO[k] = (2 * r + 1) * 608 + s * 16 + cg * 8;  // y' = 2r+1
            nAO = k + 1;
        }
    }
    int invB[4]; int nB = 0;
#pragma unroll
    for (int k = 0; k < 4; ++k) {
        const int i = w + 4 * k;
        if (i < 14) {
            const int kx = i >> 1, nt = i & 1;
            invB[k] = kx * 1024 + (nt * 32 + m) * 16 + h * 8;
            nB = k + 1;
        }
    }

    f16v acc[2][2];
    for (int t = 0; t < 2; ++t)
        for (int n = 0; n < 2; ++n)
            for (int k = 0; k < 16; ++k) acc[t][n][k] = 0.f;

    const int rA0   = ((m >> 4) << 2) + ((m >> 2) & 3);   // yo base 0..7
    const int sbase = (w << 3) + ((m & 3) << 1);          // + kx -> x slot

    auto stageAE = [&](int g) {
        const int chunk = g / 7, kz = g - chunk * 7;
        const size_t u = ((size_t)chunk * NROW
                        + (size_t)(b * PZ_ + 2 * oz + kz) * PZ_) * 608;
#pragma unroll
        for (int k = 0; k < 6; ++k)
            if (k < nAE) gl_lds16(xt + u + invAE[k], lds + (w + 4 * k) * 1024);
    };
    auto stageAO = [&](int g) {
        const int chunk = g / 7, kz = g - chunk * 7;
        const size_t u = ((size_t)chunk * NROW
                        + (size_t)(b * PZ_ + 2 * oz + kz) * PZ_) * 608;
#pragma unroll
        for (int k = 0; k < 6; ++k)
            if (k < nAO) gl_lds16(xt + u + invAO[k], lds + AO_OFF + (w + 4 * k) * 1024);
    };
    auto stageB = [&](int g, int kyv, int bsel) {
        const int chunk = g / 7, kz = g - chunk * 7;
        const size_t u = ((size_t)chunk * NTAP + (size_t)(kz * 7 + kyv) * 7) * 1024;
        char* dst = lds + B_OFF + bsel * BSZ;
#pragma unroll
        for (int k = 0; k < 4; ++k)
            if (k < nB) gl_lds16(wl + u + invB[k], dst + (w + 4 * k) * 1024);
    };

    auto compute = [&](int ky, int bsel) {
        const int abase = (ky & 1) ? AO_OFF : 0;
        const char* abp = lds + abase + (rA0 + (ky >> 1)) * AROW;
        const char* bbp = lds + B_OFF + bsel * BSZ;
#pragma unroll
        for (int kx = 0; kx < 7; ++kx) {
            const int s   = sbase + kx;
            const int cgp = h ^ ((s >> 1) & 1);
            const char* ap = abp + s * 32 + cgp * 16;
            const s8 a0 = *(const s8*)(ap);
            const s8 a1 = *(const s8*)(ap + 8 * AROW);
            const char* bp = bbp + kx * 2048 + h * 512 + m * 16;
            const s8 b0 = *(const s8*)(bp);
            const s8 b1 = *(const s8*)(bp + 1024);
            acc[0][0] = __builtin_amdgcn_mfma_f32_32x32x16_bf16(a0, b0, acc[0][0], 0, 0, 0);
            acc[0][1] = __builtin_amdgcn_mfma_f32_32x32x16_bf16(a0, b1, acc[0][1], 0, 0, 0);
            acc[1][0] = __builtin_amdgcn_mfma_f32_32x32x16_bf16(a1, b0, acc[1][0], 0, 0, 0);
            acc[1][1] = __builtin_amdgcn_mfma_f32_32x32x16_bf16(a1, b1, acc[1][1], 0, 0, 0);
        }
    };

    // ---- main loop: groups g = ks..69 step 8; taps ky order 1,3,5,0,2,4,6 ----
    const int G = (70 - ks + KSN - 1) / KSN;   // ks 0..5 -> 9, 6..7 -> 8
    const int T = G * 7;
    stageAO(ks);
    stageB(ks, 1, 0);
    __syncthreads();
    int bB = 0;
    for (int t = 0; t < T; ++t) {
        const int gi = t / 7, p = t - gi * 7;
        const int g  = ks + gi * KSN;
        const int ky = (p < 3) ? (2 * p + 1) : (2 * (p - 3));
        const int tn = t + 1;
        if (tn < T) {
            const int gin = tn / 7, pn = tn - gin * 7;
            const int kyn = (pn < 3) ? (2 * pn + 1) : (2 * (pn - 3));
            stageB(ks + gin * KSN, kyn, bB ^ 1);
        }
        if (p == 0) stageAE(g);                        // compute reads A_O
        else if (p == 3 && g + KSN < 70) stageAO(g + KSN);  // compute reads A_E
        compute(ky, bB);
        __syncthreads();                               // drains lds-DMA
        bB ^= 1;
    }

    // ---- epilogue: two-pass LDS transpose, coalesced bf16 partial stores ----
    // C/D 32x32: col(n)=lane&31, row m32=(reg&3)+8*(reg>>2)+4*h  [m74/m101]
    const int nl = lane & 31;
    f4* yb = (f4*)lds;                  // [64n][33 f4] padded = 33792 B
    __hip_bfloat16* dst0 = y4b + (size_t)ks * SLICE_E + (size_t)(b * 64) * 4096;
#pragma unroll
    for (int t = 0; t < 2; ++t) {       // yo-half
        __syncthreads();                // prior readers (or compute) done
#pragma unroll
        for (int nt = 0; nt < 2; ++nt) {
            const int n = nt * 32 + nl;
#pragma unroll
            for (int q = 0; q < 4; ++q) {
                const int rr = 2 * q + h;
                f4 v = { acc[t][nt][4*q], acc[t][nt][4*q+1],
                         acc[t][nt][4*q+2], acc[t][nt][4*q+3] };
                yb[n * 33 + rr * 4 + w] = v;
            }
        }
        __syncthreads();
        for (int j = tid; j < 2048; j += 256) {
            const int n  = j >> 5, sp = j & 31;    // sp = rr*4 + wq
            f4 v = yb[n * 33 + sp];
            const int rr = sp >> 2, wq = sp & 3;
            const int yo = t * 8 + (rr >> 2) * 4 + (rr & 3);
            bh4 p{__float2bfloat16(v.x), __float2bfloat16(v.y),
                  __float2bfloat16(v.z), __float2bfloat16(v.w)};
            *(bh4*)(dst0 + (size_t)n * 4096 + oz * 256 + yo * 16 + wq * 4) = p;
        }
    }
}

// ---------------------------------------------------------------------------
// Combine KSN bf16 partials -> f32 yc + per-(n,b) sum of squares. 256 blocks.
// ---------------------------------------------------------------------------
__global__ void combine_reduce_kernel(const __hip_bfloat16* __restrict__ y4b,
                                      float* __restrict__ yc,
                                      float* __restrict__ sums2)
{
    const int n = blockIdx.x & 63, q = blockIdx.x >> 6;
    const size_t base = ((size_t)q * 64 + n) * 4096;
    float s = 0.f;
    for (int i = threadIdx.x; i < 1024; i += 256) {
        const size_t off = base + (size_t)i * 4;
        f4 v = {0.f, 0.f, 0.f, 0.f};
#pragma unroll
        for (int k = 0; k < KSN; ++k) {
            bh4 r = *(const bh4*)(y4b + off + (size_t)k * SLICE_E);
            v.x += (float)r.x; v.y += (float)r.y;
            v.z += (float)r.z; v.w += (float)r.w;
        }
        *(f4*)(yc + off) = v;
        s += v.x * v.x + v.y * v.y + v.z * v.z + v.w * v.w;
    }
    __shared__ float red[256];
    red[threadIdx.x] = s;
    __syncthreads();
    for (int st = 128; st > 0; st >>= 1) {
        if (threadIdx.x < st) red[threadIdx.x] += red[threadIdx.x + st];
        __syncthreads();
    }
    if (threadIdx.x == 0) sums2[n * 4 + q] = red[0];
}

// ---------------------------------------------------------------------------
__global__ void finalize_kernel(const float* __restrict__ yc,
                                const float* __restrict__ sums2,
                                const float* __restrict__ g_s,
                                const float* __restrict__ g_v,
                                const float* __restrict__ bias_s,
                                float* __restrict__ out)
{
    const int idx = blockIdx.x * 256 + threadIdx.x;   // exact grid, 1M
    const int n = (idx >> 12) & 63;
    float v = yc[idx];
    if (n < 16) {
        float sum = sums2[n*4] + sums2[n*4+1] + sums2[n*4+2] + sums2[n*4+3];
        float var = sum * (1.0f / 16384.0f);
        float sc  = g_s[n] / sqrtf(var + 1e-5f);
        v = fmaxf(v * sc + bias_s[n], 0.f);
    } else {
        int u = (n - 16) / 3;
        float sum = 0.f;
        for (int k = 0; k < 12; ++k) sum += sums2[(16 + u * 3) * 4 + k];
        float var = sum * (1.0f / 49152.0f);
        v = v * (g_v[u] / sqrtf(var + 1e-5f));
    }
    out[idx] = v;
}

// ---------------------------------------------------------------------------
extern "C" void kernel_launch(void* const* d_in, const int* in_sizes, int n_in,
                              void* d_out, int out_size, void* d_ws, size_t ws_size,
                              hipStream_t stream)
{
    const float* sv    = (const float*)d_in[0];
    const float* b_ss  = (const float*)d_in[1];
    const float* w_ss  = (const float*)d_in[2];
    const float* b_sv  = (const float*)d_in[3];
    const float* w_sv  = (const float*)d_in[4];
    const float* b_st  = (const float*)d_in[5];
    const float* w_st  = (const float*)d_in[6];
    const float* b_vs  = (const float*)d_in[7];
    const float* w_vs  = (const float*)d_in[8];
    const float* b_vv  = (const float*)d_in[9];
    const float* w_vv  = (const float*)d_in[10];
    const float* b_vt  = (const float*)d_in[11];
    const float* w_vt  = (const float*)d_in[12];
    const float* bn_gs = (const float*)d_in[13];
    const float* bn_gv = (const float*)d_in[14];
    const float* bias_s= (const float*)d_in[15];
    float* out = (float*)d_out;

    char* ws = (char*)d_ws;
    constexpr size_t XT_BYTES = (size_t)10 * NROW * 1216;      // 66,588,160
    constexpr size_t WL_BYTES = (size_t)10 * NTAP * 2048;      //  7,024,640
    constexpr size_t Y4_BYTES = (size_t)KSN * SLICE_E * 2;     // 16,777,216
    constexpr size_t YC_BYTES = (size_t)4 * 64 * 4096 * 4;     //  4,194,304

    __hip_bfloat16* xt  = (__hip_bfloat16*)ws;
    __hip_bfloat16* wl  = (__hip_bfloat16*)(ws + XT_BYTES);
    __hip_bfloat16* y4b = (__hip_bfloat16*)(ws + XT_BYTES + WL_BYTES);
    float* yc    = (float*)(ws + XT_BYTES + WL_BYTES + Y4_BYTES);
    float* sums2 = (float*)(ws + XT_BYTES + WL_BYTES + Y4_BYTES + YC_BYTES);

    build_xt_kernel<<<5476, 256, 0, stream>>>(sv, xt);
    build_w_kernel<<<1372, 256, 0, stream>>>(
        b_ss, w_ss, b_sv, w_sv, b_st, w_st, b_vs, w_vs, b_vv, w_vv,
        b_vt, w_vt, wl);
    conv_mfma_kernel<<<64 * KSN, 256, 0, stream>>>(xt, wl, y4b);
    combine_reduce_kernel<<<256, 256, 0, stream>>>(y4b, yc, sums2);
    finalize_kernel<<<4096, 256, 0, stream>>>(yc, sums2, bn_gs, bn_gv, bias_s, out);
}

// Round 11
// 252.226 us; speedup vs baseline: 4.5346x; 1.0818x over previous
//
#include <hip/hip_runtime.h>
#include <hip/hip_bf16.h>

// ---------------------------------------------------------------------------
// Equivariant conv block. MFMA 32x32x16 implicit GEMM.
// R19 post-mortem: prep split/occupancy = null; non-conv budget stable at
// ~160-167us across ALL rounds (R6/R7/R8/R10 cross-check). Biggest hidden
// suspect by arithmetic: build_w (~2.3M scalar LDS reads w/ data-dependent
// addresses -> 20-45us + 4x redundant W staging). R20: build_w restructured:
// grid 343 (1 block/tap), 192 thr, thread = channel-column c computing all
// 64 n; basis-combination values bs(dn,t) HOISTED to registers once per
// thread (depend on c only); W-rows read once per u, reused across 3 dn via
// 3 accumulators. LDS reads/output 42 -> ~10; staging 4x less. All hoisted
// arrays fully unrolled (rule #20). Writes stay lane-adjacent coalesced.
// conv (106us, LDS-pipe-bound ~88us floor) + rest byte-identical to R19.
// ---------------------------------------------------------------------------

using f4  = __attribute__((ext_vector_type(4)))  float;
using f16v= __attribute__((ext_vector_type(16))) float;
using s8  = __attribute__((ext_vector_type(8)))  short;  // 8 bf16

#define C_TOT 160
#define PZ_   37
#define NTAP  343
#define NROW  (4 * PZ_ * PZ_)   // 5476 (b,z,y) rows per chunk
#define KSN   8
#define SLICE_E 1048576         // bf16 elems per partial slice (4*64*4096)

// conv LDS: A-stripe rows (1216 B data + 16 pad = 1232 stride), split by
// y'-parity: A_E = 19 rows (y'=0,2,..,36) at [0, 23552); A_O = 18 rows at
// [23552, 46080). B at 46080: [kx7][nt2][cg2][n32][16B], dbuf 2x14336.
// Total 74752 B (x2 blocks/CU = 149504 <= 160KB).
// Epilogue reuses [0, 33792) as yb[64n][33 f4].
#define AROW    1232
#define AE_ROWS 19
#define AO_ROWS 18
#define AO_OFF  23552
#define B_OFF   46080
#define BSZ     14336
#define LDS_SZ  (B_OFF + 2 * BSZ)   // 74752

__device__ __forceinline__ void gl_lds16(const void* g, void* l) {
    __builtin_amdgcn_global_load_lds(
        (const __attribute__((address_space(1))) unsigned int*)g,
        (__attribute__((address_space(3))) unsigned int*)l, 16, 0, 0);
}

__device__ __forceinline__ void pair_ij(int p, int& i, int& j) {
    if (p < 3)      { i = p; j = p; }
    else if (p == 3){ i = 0; j = 1; }
    else if (p == 4){ i = 0; j = 2; }
    else            { i = 1; j = 2; }
}

struct bf2 { __hip_bfloat16 x, y; };
struct bh4 { __hip_bfloat16 x, y, z, w; };

// ---------------------------------------------------------------------------
// build_w (R20): grid 343 = 1 block/tap, 192 threads. Threads 0..159 own
// channel-column c and compute all 64 n with register-hoisted basis combos.
// wl[chunk][tap][n][16ch] layout unchanged.
// ---------------------------------------------------------------------------
__global__ void build_w_kernel(
    const float* __restrict__ b_ss, const float* __restrict__ w_ss,
    const float* __restrict__ b_sv, const float* __restrict__ w_sv,
    const float* __restrict__ b_st, const float* __restrict__ w_st,
    const float* __restrict__ b_vs, const float* __restrict__ w_vs,
    const float* __restrict__ b_vv, const float* __restrict__ w_vv,
    const float* __restrict__ b_vt, const float* __restrict__ w_vt,
    __hip_bfloat16* __restrict__ wl)
{
    __shared__ float S[13056];
    const int tid = threadIdx.x;          // 0..191
    const int tap = blockIdx.x;           // 0..342
    float* L = S;                         // 750
    float* W = S + 768;                   // 12288
    for (int r = tid; r < 750; r += 192) {
        float v;
        if (r < 3)        v = b_ss[r * NTAP + tap];
        else if (r < 12)  v = b_sv[(r - 3) * NTAP + tap];
        else if (r < 93)  v = b_st[(r - 12) * NTAP + tap];
        else if (r < 102) v = b_vs[(r - 93) * NTAP + tap];
        else if (r < 183) v = b_vv[(r - 102) * NTAP + tap];
        else              v = b_vt[(r - 183) * NTAP + tap];
        L[r] = v;
    }
    for (int r = tid; r < 12288; r += 192) {
        float v;
        if (r < 768)       v = w_ss[r];
        else if (r < 1536) v = w_sv[r - 768];
        else if (r < 3840) v = w_st[r - 1536];
        else if (r < 4608) v = w_vs[r - 3840];
        else if (r < 6912) v = w_vv[r - 4608];
        else               v = w_vt[r - 6912];
        W[r] = v;
    }
    __syncthreads();

    if (tid < 160) {
        const int c = tid;
        const int chunk = c >> 4, cw = c & 15;
        __hip_bfloat16* dst = wl + ((size_t)chunk * NTAP + tap) * 1024 + cw;

        if (c < 16) {
            // ---- class A (scalar input ch) ----
            const float l0 = L[0], l1 = L[1], l2 = L[2];
#pragma unroll
            for (int n = 0; n < 16; ++n) {
                const float* wr = &W[(n * 16 + c) * 3];
                dst[n * 16] = __float2bfloat16(wr[0]*l0 + wr[1]*l1 + wr[2]*l2);
            }
            float bv[3][3];
#pragma unroll
            for (int dn = 0; dn < 3; ++dn)
#pragma unroll
                for (int t = 0; t < 3; ++t) bv[dn][t] = L[93 + t*3 + dn];
#pragma unroll
            for (int u = 0; u < 16; ++u) {
                const float* wr = &W[3840 + (u * 16 + c) * 3];
                const float w0 = wr[0], w1 = wr[1], w2 = wr[2];
#pragma unroll
                for (int dn = 0; dn < 3; ++dn)
                    dst[(16 + u*3 + dn) * 16] = __float2bfloat16(
                        w0*bv[dn][0] + w1*bv[dn][1] + w2*bv[dn][2]);
            }
        } else if (c < 64) {
            // ---- class B (vector input ch) ----
            const int mm = (c - 16) / 3, di = (c - 16) % 3;
            float bs0[3];
#pragma unroll
            for (int t = 0; t < 3; ++t) bs0[t] = L[3 + t*3 + di];
#pragma unroll
            for (int n = 0; n < 16; ++n) {
                const float* wr = &W[768 + (n * 16 + mm) * 3];
                dst[n * 16] = __float2bfloat16(
                    wr[0]*bs0[0] + wr[1]*bs0[1] + wr[2]*bs0[2]);
            }
            float bv[3][9];
#pragma unroll
            for (int dn = 0; dn < 3; ++dn)
#pragma unroll
                for (int t = 0; t < 9; ++t)
                    bv[dn][t] = L[102 + (t*3 + dn)*3 + di];
#pragma unroll
            for (int u = 0; u < 16; ++u) {
                const float* wr = &W[4608 + (u * 16 + mm) * 9];
                float a0 = 0.f, a1 = 0.f, a2 = 0.f;
#pragma unroll
                for (int t = 0; t < 9; ++t) {
                    const float wv = wr[t];
                    a0 += wv * bv[0][t]; a1 += wv * bv[1][t]; a2 += wv * bv[2][t];
                }
                dst[(16 + u*3 + 0) * 16] = __float2bfloat16(a0);
                dst[(16 + u*3 + 1) * 16] = __float2bfloat16(a1);
                dst[(16 + u*3 + 2) * 16] = __float2bfloat16(a2);
            }
        } else {
            // ---- class C (tensor input ch) ----
            const int q = c - 64, mm = q / 6, p = q % 6;
            int i, jj; pair_ij(p, i, jj);
            const int d1 = i*3 + jj, d2 = jj*3 + i;
            const bool dbl = (i != jj);
            float bs0[9];
#pragma unroll
            for (int t = 0; t < 9; ++t) {
                float b = L[12 + t*9 + d1];
                if (dbl) b += L[12 + t*9 + d2];
                bs0[t] = b;
            }
#pragma unroll
            for (int n = 0; n < 16; ++n) {
                const float* wr = &W[1536 + (n * 16 + mm) * 9];
                float acc = 0.f;
#pragma unroll
                for (int t = 0; t < 9; ++t) acc += wr[t] * bs0[t];
                dst[n * 16] = __float2bfloat16(acc);
            }
            float bv0[21], bv1[21], bv2[21];
#pragma unroll
            for (int t = 0; t < 21; ++t) {
                float x0 = L[183 + (t*3 + 0)*9 + d1];
                float x1 = L[183 + (t*3 + 1)*9 + d1];
                float x2 = L[183 + (t*3 + 2)*9 + d1];
                if (dbl) {
                    x0 += L[183 + (t*3 + 0)*9 + d2];
                    x1 += L[183 + (t*3 + 1)*9 + d2];
                    x2 += L[183 + (t*3 + 2)*9 + d2];
                }
                bv0[t] = x0; bv1[t] = x1; bv2[t] = x2;
            }
#pragma unroll
            for (int u = 0; u < 16; ++u) {
                const float* wr = &W[6912 + (u * 16 + mm) * 21];
                float a0 = 0.f, a1 = 0.f, a2 = 0.f;
#pragma unroll
                for (int t = 0; t < 21; ++t) {
                    const float wv = wr[t];
                    a0 += wv * bv0[t]; a1 += wv * bv1[t]; a2 += wv * bv2[t];
                }
                dst[(16 + u*3 + 0) * 16] = __float2bfloat16(a0);
                dst[(16 + u*3 + 1) * 16] = __float2bfloat16(a1);
                dst[(16 + u*3 + 2) * 16] = __float2bfloat16(a2);
            }
        }
    }
}

// ---------------------------------------------------------------------------
// build_xt: bid = (b*37 + z)*37 + y. xt[chunk][brow][s][16ch].
// Small shared (8448 B) -> 8 blocks/CU (wave-capped). Coalesced writes.
// ---------------------------------------------------------------------------
__global__ void build_xt_kernel(
    const float* __restrict__ sv, __hip_bfloat16* __restrict__ xt)
{
    __shared__ float row[2112];                  // 32*66
    const int tid = threadIdx.x;
    const int bid = blockIdx.x;                  // (b*37 + z)*37 + y
    const int y = bid % 37, z = (bid / 37) % 37, b = bid / 1369;
    const bool interior = (z >= 3 && z < 35 && y >= 3 && y < 35);
    if (interior) {
        const float* src = sv + (size_t)b * 2097152 + (z-3) * 1024 + (y-3) * 32;
        for (int f = tid; f < 2048; f += 256) {
            int ch = f >> 5, x = f & 31;
            row[x * 66 + ch] = src[(size_t)ch * 32768 + x];
        }
    }
    __syncthreads();
    for (int e2 = tid; e2 < 3040; e2 += 256) {
        const int chunk = e2 / 304;              // 0..9
        const int r     = e2 - chunk * 304;      // 0..303 (elem-pair idx)
        const int s     = r >> 3;                // 0..37
        const int cw    = (r & 7) * 2;
        const int c     = chunk * 16 + cw;
        float v0 = 0.f, v1 = 0.f;
        if (interior && s >= 3 && s < 35) {
            const int x = s - 3;
            if (c < 64) {
                v0 = row[x * 66 + c];
                v1 = row[x * 66 + c + 1];
            } else {
                int q = c - 64, u = q / 6, p = q % 6, i, j;
                pair_ij(p, i, j);
                v0 = row[x * 66 + 16 + u * 3 + i] * row[x * 66 + 16 + u * 3 + j];
                pair_ij(p + 1, i, j);
                v1 = row[x * 66 + 16 + u * 3 + i] * row[x * 66 + 16 + u * 3 + j];
            }
        }
        bf2 w{__float2bfloat16(v0), __float2bfloat16(v1)};
        *(bf2*)(xt + ((size_t)chunk * NROW + bid) * 608 + r * 2) = w;
    }
}

// ---------------------------------------------------------------------------
// Conv (R13 verbatim, verified ~106us; LDS-pipe-bound). Grid 512 (2/CU).
// Block = (b, oz, ks). K groups g=(chunk,kz) = ks..69 step 8; per group
// A-stripe staged once, parity split; taps ky = 1,3,5,0,2,4,6.
// B staged per tap (LDS dbuf). One barrier per tap.
// ---------------------------------------------------------------------------
__global__ __launch_bounds__(256, 2) void conv_mfma_kernel(
    const __hip_bfloat16* __restrict__ xt,
    const __hip_bfloat16* __restrict__ wl,
    __hip_bfloat16* __restrict__ y4b)
{
    __shared__ __align__(16) char lds[LDS_SZ];

    // T1 XCD swizzle: grid = 512 = 8 XCDs x 64.
    const int phys = blockIdx.x;
    const int bid  = (phys & 7) * (64 * KSN / 8) + (phys >> 3);

    const int low3 = bid & 7;
    const int rest = bid >> 3;
    const int ks   = rest % KSN;
    const int mb   = (rest / KSN) * 8 + low3;   // 0..63
    const int b    = mb >> 4;                   // 0..3
    const int oz   = mb & 15;                   // z-out 0..15

    const int tid  = threadIdx.x;
    const int w    = tid >> 6;          // x-quarter
    const int lane = tid & 63;
    const int m    = lane & 31;
    const int h    = lane >> 5;         // k-half (8-ch group)

    // ---- per-lane invariant staging source offsets (elements) ----
    int invAE[6]; int nAE = 0;
#pragma unroll
    for (int k = 0; k < 6; ++k) {
        const int i = w + 4 * k;
        if (i < 23) {
            const int o = i * 1024 + lane * 16;
            int r = o / AROW;
            int rem = o - r * AROW;
            if (r > AE_ROWS - 1) { r = AE_ROWS - 1; rem = 0; }
            if (rem >= 1216) rem = 0;
            const int s  = rem >> 5;
            const int cg = ((rem >> 4) & 1) ^ ((s >> 1) & 1);
            invAE[k] = (2 * r) * 608 + s * 16 + cg * 8;      // y' = 2r
            nAE = k + 1;
        }
    }
    int invAO[6]; int nAO = 0;
#pragma unroll
    for (int k = 0; k < 6; ++k) {
        const int i = w + 4 * k;
        if (i < 22) {
            const int o = i * 1024 + lane * 16;
            int r = o / AROW;
            int rem = o - r * AROW;
            if (r > AO_ROWS - 1) { r = AO_ROWS - 1; rem = 0; }
            if (rem >= 1216) rem = 0;
            const int s  = rem >> 5;
            const int cg = ((rem >> 4) & 1) ^ ((s >> 1) & 1);
            invAO[k] = (2 * r + 1) * 608 + s * 16 + cg * 8;  // y' = 2r+1
            nAO = k + 1;
        }
    }
    int invB[4]; int nB = 0;
#pragma unroll
    for (int k = 0; k < 4; ++k) {
        const int i = w + 4 * k;
        if (i < 14) {
            const int kx = i >> 1, nt = i & 1;
            invB[k] = kx * 1024 + (nt * 32 + m) * 16 + h * 8;
            nB = k + 1;
        }
    }

    f16v acc[2][2];
    for (int t = 0; t < 2; ++t)
        for (int n = 0; n < 2; ++n)
            for (int k = 0; k < 16; ++k) acc[t][n][k] = 0.f;

    const int rA0   = ((m >> 4) << 2) + ((m >> 2) & 3);   // yo base 0..7
    const int sbase = (w << 3) + ((m & 3) << 1);          // + kx -> x slot

    auto stageAE = [&](int g) {
        const int chunk = g / 7, kz = g - chunk * 7;
        const size_t u = ((size_t)chunk * NROW
                        + (size_t)(b * PZ_ + 2 * oz + kz) * PZ_) * 608;
#pragma unroll
        for (int k = 0; k < 6; ++k)
            if (k < nAE) gl_lds16(xt + u + invAE[k], lds + (w + 4 * k) * 1024);
    };
    auto stageAO = [&](int g) {
        const int chunk = g / 7, kz = g - chunk * 7;
        const size_t u = ((size_t)chunk * NROW
                        + (size_t)(b * PZ_ + 2 * oz + kz) * PZ_) * 608;
#pragma unroll
        for (int k = 0; k < 6; ++k)
            if (k < nAO) gl_lds16(xt + u + invAO[k], lds + AO_OFF + (w + 4 * k) * 1024);
    };
    auto stageB = [&](int g, int kyv, int bsel) {
        const int chunk = g / 7, kz = g - chunk * 7;
        const size_t u = ((size_t)chunk * NTAP + (size_t)(kz * 7 + kyv) * 7) * 1024;
        char* dst = lds + B_OFF + bsel * BSZ;
#pragma unroll
        for (int k = 0; k < 4; ++k)
            if (k < nB) gl_lds16(wl + u + invB[k], dst + (w + 4 * k) * 1024);
    };

    auto compute = [&](int ky, int bsel) {
        const int abase = (ky & 1) ? AO_OFF : 0;
        const char* abp = lds + abase + (rA0 + (ky >> 1)) * AROW;
        const char* bbp = lds + B_OFF + bsel * BSZ;
#pragma unroll
        for (int kx = 0; kx < 7; ++kx) {
            const int s   = sbase + kx;
            const int cgp = h ^ ((s >> 1) & 1);
            const char* ap = abp + s * 32 + cgp * 16;
            const s8 a0 = *(const s8*)(ap);
            const s8 a1 = *(const s8*)(ap + 8 * AROW);
            const char* bp = bbp + kx * 2048 + h * 512 + m * 16;
            const s8 b0 = *(const s8*)(bp);
            const s8 b1 = *(const s8*)(bp + 1024);
            acc[0][0] = __builtin_amdgcn_mfma_f32_32x32x16_bf16(a0, b0, acc[0][0], 0, 0, 0);
            acc[0][1] = __builtin_amdgcn_mfma_f32_32x32x16_bf16(a0, b1, acc[0][1], 0, 0, 0);
            acc[1][0] = __builtin_amdgcn_mfma_f32_32x32x16_bf16(a1, b0, acc[1][0], 0, 0, 0);
            acc[1][1] = __builtin_amdgcn_mfma_f32_32x32x16_bf16(a1, b1, acc[1][1], 0, 0, 0);
        }
    };

    // ---- main loop: groups g = ks..69 step 8; taps ky order 1,3,5,0,2,4,6 ----
    const int G = (70 - ks + KSN - 1) / KSN;   // ks 0..5 -> 9, 6..7 -> 8
    const int T = G * 7;
    stageAO(ks);
    stageB(ks, 1, 0);
    __syncthreads();
    int bB = 0;
    for (int t = 0; t < T; ++t) {
        const int gi = t / 7, p = t - gi * 7;
        const int g  = ks + gi * KSN;
        const int ky = (p < 3) ? (2 * p + 1) : (2 * (p - 3));
        const int tn = t + 1;
        if (tn < T) {
            const int gin = tn / 7, pn = tn - gin * 7;
            const int kyn = (pn < 3) ? (2 * pn + 1) : (2 * (pn - 3));
            stageB(ks + gin * KSN, kyn, bB ^ 1);
        }
        if (p == 0) stageAE(g);                        // compute reads A_O
        else if (p == 3 && g + KSN < 70) stageAO(g + KSN);  // compute reads A_E
        compute(ky, bB);
        __syncthreads();                               // drains lds-DMA
        bB ^= 1;
    }

    // ---- epilogue: two-pass LDS transpose, coalesced bf16 partial stores ----
    // C/D 32x32: col(n)=lane&31, row m32=(reg&3)+8*(reg>>2)+4*h  [m74/m101]
    const int nl = lane & 31;
    f4* yb = (f4*)lds;                  // [64n][33 f4] padded = 33792 B
    __hip_bfloat16* dst0 = y4b + (size_t)ks * SLICE_E + (size_t)(b * 64) * 4096;
#pragma unroll
    for (int t = 0; t < 2; ++t) {       // yo-half
        __syncthreads();                // prior readers (or compute) done
#pragma unroll
        for (int nt = 0; nt < 2; ++nt) {
            const int n = nt * 32 + nl;
#pragma unroll
            for (int q = 0; q < 4; ++q) {
                const int rr = 2 * q + h;
                f4 v = { acc[t][nt][4*q], acc[t][nt][4*q+1],
                         acc[t][nt][4*q+2], acc[t][nt][4*q+3] };
                yb[n * 33 + rr * 4 + w] = v;
            }
        }
        __syncthreads();
        for (int j = tid; j < 2048; j += 256) {
            const int n  = j >> 5, sp = j & 31;    // sp = rr*4 + wq
            f4 v = yb[n * 33 + sp];
            const int rr = sp >> 2, wq = sp & 3;
            const int yo = t * 8 + (rr >> 2) * 4 + (rr & 3);
            bh4 p{__float2bfloat16(v.x), __float2bfloat16(v.y),
                  __float2bfloat16(v.z), __float2bfloat16(v.w)};
            *(bh4*)(dst0 + (size_t)n * 4096 + oz * 256 + yo * 16 + wq * 4) = p;
        }
    }
}

// ---------------------------------------------------------------------------
// Combine KSN bf16 partials -> f32 yc + per-(n,b) sum of squares. 256 blocks.
// ---------------------------------------------------------------------------
__global__ void combine_reduce_kernel(const __hip_bfloat16* __restrict__ y4b,
                                      float* __restrict__ yc,
                                      float* __restrict__ sums2)
{
    const int n = blockIdx.x & 63, q = blockIdx.x >> 6;
    const size_t base = ((size_t)q * 64 + n) * 4096;
    float s = 0.f;
    for (int i = threadIdx.x; i < 1024; i += 256) {
        const size_t off = base + (size_t)i * 4;
        f4 v = {0.f, 0.f, 0.f, 0.f};
#pragma unroll
        for (int k = 0; k < KSN; ++k) {
            bh4 r = *(const bh4*)(y4b + off + (size_t)k * SLICE_E);
            v.x += (float)r.x; v.y += (float)r.y;
            v.z += (float)r.z; v.w += (float)r.w;
        }
        *(f4*)(yc + off) = v;
        s += v.x * v.x + v.y * v.y + v.z * v.z + v.w * v.w;
    }
    __shared__ float red[256];
    red[threadIdx.x] = s;
    __syncthreads();
    for (int st = 128; st > 0; st >>= 1) {
        if (threadIdx.x < st) red[threadIdx.x] += red[threadIdx.x + st];
        __syncthreads();
    }
    if (threadIdx.x == 0) sums2[n * 4 + q] = red[0];
}

// ---------------------------------------------------------------------------
__global__ void finalize_kernel(const float* __restrict__ yc,
                                const float* __restrict__ sums2,
                                const float* __restrict__ g_s,
                                const float* __restrict__ g_v,
                                const float* __restrict__ bias_s,
                                float* __restrict__ out)
{
    const int idx = blockIdx.x * 256 + threadIdx.x;   // exact grid, 1M
    const int n = (idx >> 12) & 63;
    float v = yc[idx];
    if (n < 16) {
        float sum = sums2[n*4] + sums2[n*4+1] + sums2[n*4+2] + sums2[n*4+3];
        float var = sum * (1.0f / 16384.0f);
        float sc  = g_s[n] / sqrtf(var + 1e-5f);
        v = fmaxf(v * sc + bias_s[n], 0.f);
    } else {
        int u = (n - 16) / 3;
        float sum = 0.f;
        for (int k = 0; k < 12; ++k) sum += sums2[(16 + u * 3) * 4 + k];
        float var = sum * (1.0f / 49152.0f);
        v = v * (g_v[u] / sqrtf(var + 1e-5f));
    }
    out[idx] = v;
}

// ---------------------------------------------------------------------------
extern "C" void kernel_launch(void* const* d_in, const int* in_sizes, int n_in,
                              void* d_out, int out_size, void* d_ws, size_t ws_size,
                              hipStream_t stream)
{
    const float* sv    = (const float*)d_in[0];
    const float* b_ss  = (const float*)d_in[1];
    const float* w_ss  = (const float*)d_in[2];
    const float* b_sv  = (const float*)d_in[3];
    const float* w_sv  = (const float*)d_in[4];
    const float* b_st  = (const float*)d_in[5];
    const float* w_st  = (const float*)d_in[6];
    const float* b_vs  = (const float*)d_in[7];
    const float* w_vs  = (const float*)d_in[8];
    const float* b_vv  = (const float*)d_in[9];
    const float* w_vv  = (const float*)d_in[10];
    const float* b_vt  = (const float*)d_in[11];
    const float* w_vt  = (const float*)d_in[12];
    const float* bn_gs = (const float*)d_in[13];
    const float* bn_gv = (const float*)d_in[14];
    const float* bias_s= (const float*)d_in[15];
    float* out = (float*)d_out;

    char* ws = (char*)d_ws;
    constexpr size_t XT_BYTES = (size_t)10 * NROW * 1216;      // 66,588,160
    constexpr size_t WL_BYTES = (size_t)10 * NTAP * 2048;      //  7,024,640
    constexpr size_t Y4_BYTES = (size_t)KSN * SLICE_E * 2;     // 16,777,216
    constexpr size_t YC_BYTES = (size_t)4 * 64 * 4096 * 4;     //  4,194,304

    __hip_bfloat16* xt  = (__hip_bfloat16*)ws;
    __hip_bfloat16* wl  = (__hip_bfloat16*)(ws + XT_BYTES);
    __hip_bfloat16* y4b = (__hip_bfloat16*)(ws + XT_BYTES + WL_BYTES);
    float* yc    = (float*)(ws + XT_BYTES + WL_BYTES + Y4_BYTES);
    float* sums2 = (float*)(ws + XT_BYTES + WL_BYTES + Y4_BYTES + YC_BYTES);

    build_xt_kernel<<<5476, 256, 0, stream>>>(sv, xt);
    build_w_kernel<<<343, 192, 0, stream>>>(
        b_ss, w_ss, b_sv, w_sv, b_st, w_st, b_vs, w_vs, b_vv, w_vv,
        b_vt, w_vt, wl);
    conv_mfma_kernel<<<64 * KSN, 256, 0, stream>>>(xt, wl, y4b);
    combine_reduce_kernel<<<256, 256, 0, stream>>>(y4b, yc, sums2);
    finalize_kernel<<<4096, 256, 0, stream>>>(yc, sums2, bn_gs, bn_gv, bias_s, out);
}